// Round 7
// baseline (23293.443 us; speedup 1.0000x reference)
//
#include <hip/hip_runtime.h>

// ResidualVectorQuantizer: B=16, D=512, F=1500, Q=8, C=1024
#define B_ 16
#define D_ 512
#define F_ 1500
#define N_ (B_*F_)   // 24000
#define Q_ 8
#define C_ 1024

constexpr int NBLK  = (N_ + 255) / 256;   // 94
constexpr int UPDBLK = 4 * NBLK;          // 376 (4 d-segments of 128)

// ---------------- init: res2[d][b*F+f] = latents[b][d][f] ----------------
__global__ void k_init(const float* __restrict__ lat, float* __restrict__ res2) {
    int bi = blockIdx.x;            // bi = b*512 + d
    int d = bi & 511, b = bi >> 9;
    const float* src = lat + (size_t)bi * F_;
    float* dst = res2 + (size_t)d * N_ + (size_t)b * F_;
    for (int f = threadIdx.x; f < F_; f += 256) dst[f] = src[f];
}

// ---------------- codebook transpose: cbT[q][d][c] = cb[q][c][d] ----------------
__global__ void k_transpose_cb(const float* __restrict__ cb, float* __restrict__ cbT) {
    __shared__ float tile[32][33];
    int bi = blockIdx.x;            // q*512 + cblk*16 + dblk
    int q = bi >> 9;
    int rem = bi & 511;
    int cblk = rem >> 4, dblk = rem & 15;
    int tx = threadIdx.x & 31, ty = threadIdx.x >> 5;  // 32 x 8
    const float* src = cb + ((size_t)q * C_ + (size_t)cblk * 32) * D_ + dblk * 32;
    for (int i = ty; i < 32; i += 8) tile[i][tx] = src[(size_t)i * D_ + tx];
    __syncthreads();
    float* dst = cbT + ((size_t)q * D_ + (size_t)dblk * 32) * C_ + cblk * 32;
    for (int i = ty; i < 32; i += 8) dst[(size_t)i * C_ + tx] = tile[tx][i];
}

// ---------------- H[q*C+c] = np.sum(cb*cb, axis=1), numpy pairwise fp32 ----------------
__global__ void k_cbnormP(const float* __restrict__ cb, float* __restrict__ Hq) {
#pragma clang fp contract(off)
    int wid = blockIdx.x * 256 + threadIdx.x;   // q*C + c
    const float* p = cb + (size_t)wid * D_;
    float L[4];
#pragma unroll
    for (int l = 0; l < 4; ++l) {
        const float* pl = p + l * 128;
        float r[8];
#pragma unroll
        for (int j = 0; j < 8; ++j) { float x = pl[j]; r[j] = x * x; }
        for (int i = 8; i < 128; i += 8) {
#pragma unroll
            for (int j = 0; j < 8; ++j) { float x = pl[i + j]; r[j] = r[j] + x * x; }
        }
        L[l] = ((r[0] + r[1]) + (r[2] + r[3])) + ((r[4] + r[5]) + (r[6] + r[7]));
    }
    Hq[wid] = (L[0] + L[1]) + (L[2] + L[3]);
}

// ---------------- initial S partials (pairwise leaves of 128): Sp[l][n] ----------------
__global__ void k_rownorm4(const float* __restrict__ res2, float* __restrict__ Sp) {
#pragma clang fp contract(off)
    int n = blockIdx.x * 256 + threadIdx.x;
    if (n >= N_) return;
#pragma unroll
    for (int l = 0; l < 4; ++l) {
        const float* p = res2 + (size_t)(l * 128) * N_ + n;
        float r[8];
#pragma unroll
        for (int j = 0; j < 8; ++j) { float x = p[(size_t)j * N_]; r[j] = x * x; }
        for (int i = 8; i < 128; i += 8) {
#pragma unroll
            for (int j = 0; j < 8; ++j) { float x = p[(size_t)(i + j) * N_]; r[j] = r[j] + x * x; }
        }
        Sp[(size_t)l * N_ + n] = ((r[0] + r[1]) + (r[2] + r[3])) + ((r[4] + r[5]) + (r[6] + r[7]));
    }
}

// ---------------- distance + argmin, fp32, single sequential FMA chain (verified) ----------------
// block: 256 threads, 64 rows x 1024 cols; per-thread 4 rows x 8 cols.
__global__ __launch_bounds__(256) void k_dist(
        const float* __restrict__ res2, const float* __restrict__ cb,
        const float* __restrict__ Hq, const float* __restrict__ Sp,
        int* __restrict__ codes, int q) {
    __shared__ float xs[64][67];     // [n][d-chunk], odd word stride (2-way max)
    __shared__ float cs[128][67];    // [c][d-chunk]
    __shared__ float redv[16][64];
    __shared__ int   redi[16][64];

    const int t = threadIdx.x;
    const int n0 = blockIdx.x * 64;
    const int tr = t & 15, tc = t >> 4;
    const float* cbq = cb + (size_t)q * ((size_t)C_ * D_);
    const float* Hqq = Hq + (size_t)q * C_;

    float S[4];
    {
#pragma clang fp contract(off)
#pragma unroll
        for (int r = 0; r < 4; ++r) {
            int n = n0 + 4 * tr + r;
            S[r] = (Sp[n] + Sp[N_ + n]) + (Sp[2 * N_ + n] + Sp[3 * N_ + n]);
        }
    }

    float bestv[4] = {3.4e38f, 3.4e38f, 3.4e38f, 3.4e38f};
    int   besti[4] = {0, 0, 0, 0};

    for (int c0 = 0; c0 < C_; c0 += 128) {
        float acc[4][8];
#pragma unroll
        for (int r = 0; r < 4; ++r)
#pragma unroll
            for (int k = 0; k < 8; ++k) acc[r][k] = 0.0f;

        for (int dc = 0; dc < D_; dc += 64) {
            __syncthreads();
            {   // stage X: 64 rows x 64 d; lane = row (writes 2-way max)
                int j = t & 63, dd0 = t >> 6;
#pragma unroll
                for (int k = 0; k < 16; ++k) {
                    int dd = dd0 + 4 * k;
                    xs[j][dd] = res2[(size_t)(dc + dd) * N_ + n0 + j];
                }
            }
            {   // stage CB: 128 rows x 64 d (float2)
#pragma unroll
                for (int k = 0; k < 16; ++k) {
                    int idx = t + k * 256;          // 0..4095
                    int r = idx >> 5;               // 0..127
                    int d2 = idx & 31;
                    const float2 v = *(const float2*)(cbq + (size_t)(c0 + r) * D_ + dc + 2 * d2);
                    *(float2*)(&cs[r][2 * d2]) = v;
                }
            }
            __syncthreads();

            const float2* xp0 = (const float2*)(&xs[4 * tr + 0][0]);
            const float2* xp1 = (const float2*)(&xs[4 * tr + 1][0]);
            const float2* xp2 = (const float2*)(&xs[4 * tr + 2][0]);
            const float2* xp3 = (const float2*)(&xs[4 * tr + 3][0]);
            const float2* cp0 = (const float2*)(&cs[8 * tc + 0][0]);
            const float2* cp1 = (const float2*)(&cs[8 * tc + 1][0]);
            const float2* cp2 = (const float2*)(&cs[8 * tc + 2][0]);
            const float2* cp3 = (const float2*)(&cs[8 * tc + 3][0]);
            const float2* cp4 = (const float2*)(&cs[8 * tc + 4][0]);
            const float2* cp5 = (const float2*)(&cs[8 * tc + 5][0]);
            const float2* cp6 = (const float2*)(&cs[8 * tc + 6][0]);
            const float2* cp7 = (const float2*)(&cs[8 * tc + 7][0]);
#pragma unroll 8
            for (int d2 = 0; d2 < 32; ++d2) {
                const float2 x0 = xp0[d2], x1 = xp1[d2], x2 = xp2[d2], x3 = xp3[d2];
                // strict d-ascending fused-FMA chain per cell (verified exact)
#define STEP(K, CP) { const float2 cv = CP[d2]; \
                acc[0][K] = fmaf(x0.x, cv.x, acc[0][K]); acc[0][K] = fmaf(x0.y, cv.y, acc[0][K]); \
                acc[1][K] = fmaf(x1.x, cv.x, acc[1][K]); acc[1][K] = fmaf(x1.y, cv.y, acc[1][K]); \
                acc[2][K] = fmaf(x2.x, cv.x, acc[2][K]); acc[2][K] = fmaf(x2.y, cv.y, acc[2][K]); \
                acc[3][K] = fmaf(x3.x, cv.x, acc[3][K]); acc[3][K] = fmaf(x3.y, cv.y, acc[3][K]); }
                STEP(0, cp0) STEP(1, cp1) STEP(2, cp2) STEP(3, cp3)
                STEP(4, cp4) STEP(5, cp5) STEP(6, cp6) STEP(7, cp7)
#undef STEP
            }
        }

        {   // dist = fl(fl(S - 2A) + H), fp32; running best, strict <
#pragma clang fp contract(off)
#pragma unroll
            for (int k = 0; k < 8; ++k) {
                int c = c0 + 8 * tc + k;
                float h = Hqq[c];
#pragma unroll
                for (int r = 0; r < 4; ++r) {
                    float tv = S[r] - 2.0f * acc[r][k];
                    float v = tv + h;
                    if (v < bestv[r]) { bestv[r] = v; besti[r] = c; }
                }
            }
        }
    }

#pragma unroll
    for (int r = 0; r < 4; ++r) {
        redv[tc][4 * tr + r] = bestv[r];
        redi[tc][4 * tr + r] = besti[r];
    }
    __syncthreads();
    if (t < 64) {
        float bv = redv[0][t]; int bidx = redi[0][t];
#pragma unroll
        for (int j = 1; j < 16; ++j) {
            float v = redv[j][t]; int ci = redi[j][t];
            if (v < bv || (v == bv && ci < bidx)) { bv = v; bidx = ci; }
        }
        codes[(size_t)q * N_ + n0 + t] = bidx;
    }
}

// ---------------- fused residual update + next-stage S partials + loss partials ----------------
__global__ __launch_bounds__(256) void k_upd(
        float* __restrict__ res2, const float* __restrict__ cbT,
        const int* __restrict__ codes, float* __restrict__ Sp,
        double* __restrict__ part, int q) {
#pragma clang fp contract(off)
    int seg = blockIdx.x / NBLK;          // 0..3
    int nb  = blockIdx.x % NBLK;
    int n = nb * 256 + threadIdx.x;
    float L = 0.0f;
    if (n < N_) {
        int idx = codes[(size_t)q * N_ + n];
        const float* crow = cbT + ((size_t)(q * 512 + seg * 128)) * C_ + idx;
        float* rp = res2 + (size_t)(seg * 128) * N_ + n;
        float r8[8];
#pragma unroll
        for (int j = 0; j < 8; ++j) {
            float r = rp[(size_t)j * N_] - crow[(size_t)j * C_];
            rp[(size_t)j * N_] = r;
            r8[j] = r * r;
        }
        for (int i = 8; i < 128; i += 8) {
#pragma unroll
            for (int j = 0; j < 8; ++j) {
                float r = rp[(size_t)(i + j) * N_] - crow[(size_t)(i + j) * C_];
                rp[(size_t)(i + j) * N_] = r;
                r8[j] = r8[j] + r * r;
            }
        }
        L = ((r8[0] + r8[1]) + (r8[2] + r8[3])) + ((r8[4] + r8[5]) + (r8[6] + r8[7]));
        Sp[(size_t)seg * N_ + n] = L;
    }
    double s = (double)L;
#pragma unroll
    for (int off = 32; off; off >>= 1) s += __shfl_down(s, off, 64);
    __shared__ double sred[4];
    int lane = threadIdx.x & 63, w = threadIdx.x >> 6;
    if (lane == 0) sred[w] = s;
    __syncthreads();
    if (threadIdx.x == 0)
        part[(size_t)q * UPDBLK + blockIdx.x] = sred[0] + sred[1] + sred[2] + sred[3];
}

// ---------------- outputs ----------------
__global__ void k_out0(const float* __restrict__ lat, const float* __restrict__ res2,
                       float* __restrict__ out) {
    int bi = blockIdx.x;            // b*512 + d
    int d = bi & 511, b = bi >> 9;
    const float* lp = lat + (size_t)bi * F_;
    const float* rp = res2 + (size_t)d * N_ + (size_t)b * F_;
    float* op = out + (size_t)bi * F_;
    for (int f = threadIdx.x; f < F_; f += 256) op[f] = lp[f] - rp[f];
}

__global__ void k_codes(const int* __restrict__ codes, float* __restrict__ out1) {
    int bi = blockIdx.x;            // b*8 + q
    int q = bi & 7, b = bi >> 3;
    for (int f = threadIdx.x; f < F_; f += 256)
        out1[(size_t)bi * F_ + f] = (float)codes[(size_t)q * N_ + (size_t)b * F_ + f];
}

__global__ void k_loss(const double* __restrict__ part, float* __restrict__ out2) {
    double s = 0.0;
    for (int i = threadIdx.x; i < Q_ * UPDBLK; i += 256) s += part[i];
#pragma unroll
    for (int off = 32; off; off >>= 1) s += __shfl_down(s, off, 64);
    __shared__ double red[4];
    int lane = threadIdx.x & 63, w = threadIdx.x >> 6;
    if (lane == 0) red[w] = s;
    __syncthreads();
    if (threadIdx.x == 0) {
        double tot = red[0] + red[1] + red[2] + red[3];
        float val = (float)(tot / ((double)Q_ * (double)B_ * (double)D_ * (double)F_));
        out2[0] = val;   // commitment_loss
        out2[1] = val;   // codebook_loss (numerically identical)
    }
}

extern "C" void kernel_launch(void* const* d_in, const int* in_sizes, int n_in,
                              void* d_out, int out_size, void* d_ws, size_t ws_size,
                              hipStream_t stream) {
    const float* lat = (const float*)d_in[0];   // [16,512,1500] fp32
    const float* cb  = (const float*)d_in[1];   // [8,1024,512]  fp32
    char* ws = (char*)d_ws;
    float*  res2  = (float*)(ws);                 // 49,152,000 B
    float*  cbT   = (float*)(ws + 49152000);      // 16,777,216 B
    int*    codes = (int*)  (ws + 65929216);      //    768,000 B
    float*  Hq    = (float*)(ws + 66697216);      //     32,768 B
    float*  Sp    = (float*)(ws + 66729984);      //    384,000 B (4 x 24000 f32)
    double* part  = (double*)(ws + 67113984);     //     24,064 B (8 x 376 f64)
    float* out = (float*)d_out;

    hipLaunchKernelGGL(k_init,         dim3(B_ * D_), dim3(256), 0, stream, lat, res2);
    hipLaunchKernelGGL(k_transpose_cb, dim3(Q_ * 512), dim3(256), 0, stream, cb, cbT);
    hipLaunchKernelGGL(k_cbnormP,      dim3(Q_ * C_ / 256), dim3(256), 0, stream, cb, Hq);
    hipLaunchKernelGGL(k_rownorm4,     dim3(NBLK), dim3(256), 0, stream, res2, Sp);

    for (int q = 0; q < Q_; ++q) {
        hipLaunchKernelGGL(k_dist, dim3(N_ / 64), dim3(256), 0, stream,
                           res2, cb, Hq, Sp, codes, q);
        hipLaunchKernelGGL(k_upd,  dim3(UPDBLK), dim3(256), 0, stream,
                           res2, cbT, codes, Sp, part, q);
    }

    hipLaunchKernelGGL(k_out0,  dim3(B_ * D_), dim3(256), 0, stream, lat, res2, out);
    hipLaunchKernelGGL(k_codes, dim3(B_ * Q_), dim3(256), 0, stream, codes, out + 12288000);
    hipLaunchKernelGGL(k_loss,  dim3(1), dim3(256), 0, stream, part, out + 12480000);
}

// Round 8
// 11791.180 us; speedup vs baseline: 1.9755x; 1.9755x over previous
//
#include <hip/hip_runtime.h>
#include <hip/hip_fp16.h>

// ResidualVectorQuantizer: B=16, D=512, F=1500, Q=8, C=1024
#define B_ 16
#define D_ 512
#define F_ 1500
#define N_ (B_*F_)   // 24000
#define Q_ 8
#define C_ 1024

constexpr int NBLK  = (N_ + 255) / 256;   // 94
constexpr int UPDBLK = 4 * NBLK;          // 376
constexpr int MPAD = 24064;               // padded rows for GEMM (188*128)

typedef __attribute__((ext_vector_type(8))) short bf16x8;
typedef __attribute__((ext_vector_type(4))) short bf16x4;
typedef __attribute__((ext_vector_type(4))) float f32x4;

__device__ __forceinline__ short f2bf(float f) {   // RNE bf16 (screen-side, approx ok)
    unsigned u = __float_as_uint(f);
    u += 0x7FFFu + ((u >> 16) & 1u);
    return (short)(u >> 16);
}
__device__ __forceinline__ float bf2f(short h) {
    return __uint_as_float(((unsigned)(unsigned short)h) << 16);
}

// ---------------- init: res2[d][b*F+f] = latents[b][d][f] ----------------
__global__ void k_init(const float* __restrict__ lat, float* __restrict__ res2) {
    int bi = blockIdx.x;            // b*512 + d
    int d = bi & 511, b = bi >> 9;
    const float* src = lat + (size_t)bi * F_;
    float* dst = res2 + (size_t)d * N_ + (size_t)b * F_;
    for (int f = threadIdx.x; f < F_; f += 256) dst[f] = src[f];
}

// ---------------- H[q*C+c] = np.sum(cb*cb, axis=1), numpy pairwise fp32 (verified) ----------------
__global__ void k_cbnormP(const float* __restrict__ cb, float* __restrict__ Hq) {
#pragma clang fp contract(off)
    int wid = blockIdx.x * 256 + threadIdx.x;
    const float* p = cb + (size_t)wid * D_;
    float L[4];
#pragma unroll
    for (int l = 0; l < 4; ++l) {
        const float* pl = p + l * 128;
        float r[8];
#pragma unroll
        for (int j = 0; j < 8; ++j) { float x = pl[j]; r[j] = x * x; }
        for (int i = 8; i < 128; i += 8) {
#pragma unroll
            for (int j = 0; j < 8; ++j) { float x = pl[i + j]; r[j] = r[j] + x * x; }
        }
        L[l] = ((r[0] + r[1]) + (r[2] + r[3])) + ((r[4] + r[5]) + (r[6] + r[7]));
    }
    Hq[wid] = (L[0] + L[1]) + (L[2] + L[3]);
}

// ---------------- initial S partials (pairwise leaves of 128) (verified) ----------------
__global__ void k_rownorm4(const float* __restrict__ res2, float* __restrict__ Sp) {
#pragma clang fp contract(off)
    int n = blockIdx.x * 256 + threadIdx.x;
    if (n >= N_) return;
#pragma unroll
    for (int l = 0; l < 4; ++l) {
        const float* p = res2 + (size_t)(l * 128) * N_ + n;
        float r[8];
#pragma unroll
        for (int j = 0; j < 8; ++j) { float x = p[(size_t)j * N_]; r[j] = x * x; }
        for (int i = 8; i < 128; i += 8) {
#pragma unroll
            for (int j = 0; j < 8; ++j) { float x = p[(size_t)(i + j) * N_]; r[j] = r[j] + x * x; }
        }
        Sp[(size_t)l * N_ + n] = ((r[0] + r[1]) + (r[2] + r[3])) + ((r[4] + r[5]) + (r[6] + r[7]));
    }
}

// ---------------- Sn[n] = pairwise top-join of Sp (verified S formula) ----------------
__global__ void k_ssum(const float* __restrict__ Sp, float* __restrict__ Sn) {
#pragma clang fp contract(off)
    int n = blockIdx.x * 256 + threadIdx.x;
    if (n >= N_) return;
    Sn[n] = (Sp[n] + Sp[N_ + n]) + (Sp[2 * N_ + n] + Sp[3 * N_ + n]);
}

// ---------------- MFMA screen GEMM: Dapx[n][c] = fp16(H[c] - 2*A_mfma) ----------------
// bf16x2 split: A ~= xh*ch + xh*cl + xl*ch. Tile 128n x 128c, K-chunks of 64.
#define LSTR 80   // LDS row stride in bf16 elems (64 data + 16 pad -> 4-way max)
__global__ __launch_bounds__(256) void k_gemm(
        const float* __restrict__ res2, const float* __restrict__ cb,
        const float* __restrict__ Hq, __half* __restrict__ Dh, int q) {
    __shared__ short xh[128 * LSTR], xl[128 * LSTR];
    __shared__ short ch[128 * LSTR], cl[128 * LSTR];
    const int t = threadIdx.x;
    const int n0 = blockIdx.x * 128;
    const int c0 = blockIdx.y * 128;
    const int l = t & 63, w = t >> 6;
    const int wr = w >> 1, wc = w & 1;
    const float* cbq = cb + (size_t)q * ((size_t)C_ * D_);

    f32x4 acc[4][4];
#pragma unroll
    for (int i = 0; i < 4; ++i)
#pragma unroll
        for (int j = 0; j < 4; ++j) { acc[i][j][0]=0.f; acc[i][j][1]=0.f; acc[i][j][2]=0.f; acc[i][j][3]=0.f; }

    for (int kc = 0; kc < D_; kc += 64) {
        __syncthreads();
        // --- stage X: 128 n-rows x 64 d, transpose from res2[d][n]; split h/l ---
#pragma unroll
        for (int p = 0; p < 4; ++p) {
            int g = p * 256 + t;
            int d8 = g & 7, n = g >> 3;
            int gd = kc + d8 * 8;
            float v[8];
#pragma unroll
            for (int i = 0; i < 8; ++i) v[i] = res2[(size_t)(gd + i) * N_ + n0 + n];
            bf16x8 hv, lv;
#pragma unroll
            for (int i = 0; i < 8; ++i) {
                short h = f2bf(v[i]);
                hv[i] = h;
                lv[i] = f2bf(v[i] - bf2f(h));
            }
            *(bf16x8*)(&xh[n * LSTR + d8 * 8]) = hv;
            *(bf16x8*)(&xl[n * LSTR + d8 * 8]) = lv;
        }
        // --- stage C: 128 c-rows x 64 d from cb[c][d]; split h/l ---
#pragma unroll
        for (int p = 0; p < 8; ++p) {
            int g = p * 256 + t;
            int cr = g >> 4, d4 = (g & 15) * 4;
            float4 v = *(const float4*)(cbq + (size_t)(c0 + cr) * D_ + kc + d4);
            bf16x4 hv, lv;
            float vv[4] = {v.x, v.y, v.z, v.w};
#pragma unroll
            for (int i = 0; i < 4; ++i) {
                short h = f2bf(vv[i]);
                hv[i] = h;
                lv[i] = f2bf(vv[i] - bf2f(h));
            }
            *(bf16x4*)(&ch[cr * LSTR + d4]) = hv;
            *(bf16x4*)(&cl[cr * LSTR + d4]) = lv;
        }
        __syncthreads();

#pragma unroll
        for (int kf = 0; kf < 2; ++kf) {
            const int ko = kf * 32 + (l >> 4) * 8;
            bf16x8 ah[4], al[4], bh[4], bl[4];
#pragma unroll
            for (int i = 0; i < 4; ++i) {
                int xr = wr * 64 + i * 16 + (l & 15);
                ah[i] = *(const bf16x8*)(&xh[xr * LSTR + ko]);
                al[i] = *(const bf16x8*)(&xl[xr * LSTR + ko]);
                int cr = wc * 64 + i * 16 + (l & 15);
                bh[i] = *(const bf16x8*)(&ch[cr * LSTR + ko]);
                bl[i] = *(const bf16x8*)(&cl[cr * LSTR + ko]);
            }
#pragma unroll
            for (int i = 0; i < 4; ++i)
#pragma unroll
                for (int j = 0; j < 4; ++j) {
                    acc[i][j] = __builtin_amdgcn_mfma_f32_16x16x32_bf16(ah[i], bh[j], acc[i][j], 0, 0, 0);
                    acc[i][j] = __builtin_amdgcn_mfma_f32_16x16x32_bf16(ah[i], bl[j], acc[i][j], 0, 0, 0);
                    acc[i][j] = __builtin_amdgcn_mfma_f32_16x16x32_bf16(al[i], bh[j], acc[i][j], 0, 0, 0);
                }
        }
    }

    // --- epilogue: Dapx = fp16(H - 2A); C/D layout col=lane&15, row=(lane>>4)*4+reg ---
    const float* Hqq = Hq + (size_t)q * C_;
#pragma unroll
    for (int i = 0; i < 4; ++i)
#pragma unroll
        for (int j = 0; j < 4; ++j) {
            int c = c0 + wc * 64 + j * 16 + (l & 15);
            float h = Hqq[c];
#pragma unroll
            for (int r = 0; r < 4; ++r) {
                int n = n0 + wr * 64 + i * 16 + (l >> 4) * 4 + r;
                float v = h - 2.0f * acc[i][j][r];
                Dh[(size_t)n * C_ + c] = __float2half(v);
            }
        }
}

// ---------------- screen + exact rescore (bit-exact chain, verified) ----------------
__global__ __launch_bounds__(256) void k_screen(
        const __half* __restrict__ Dh, const float* __restrict__ res2,
        const float* __restrict__ cb, const float* __restrict__ Hq,
        const float* __restrict__ Sn, int* __restrict__ codes, int q) {
    int n = blockIdx.x * 256 + threadIdx.x;
    bool valid = (n < N_);
    const __half* drow = Dh + (size_t)(valid ? n : 0) * C_;

    float mv = 3.4e38f;
    for (int c = 0; c < C_; ++c) {
        float v = __half2float(drow[c]);
        if (v < mv) mv = v;
    }
    const float thr = mv + 4e-3f;

    int c1 = -1, c2 = -1, c3 = -1, c4 = -1, cnt = 0;
    for (int c = 0; c < C_; ++c) {
        float v = __half2float(drow[c]);
        if (v <= thr) {
            if (cnt == 0) c1 = c; else if (cnt == 1) c2 = c;
            else if (cnt == 2) c3 = c; else if (cnt == 3) c4 = c;
            ++cnt;
        }
    }
    if (!valid) cnt = 0;

    const float S = valid ? Sn[n] : 0.0f;
    const float* cbq = cb + (size_t)q * ((size_t)C_ * D_);
    const float* Hqq = Hq + (size_t)q * C_;
    const float* xcol = res2 + (valid ? n : 0);

    float bestv = 3.4e38f; int besti = 0;
    if (cnt <= 4) {
#pragma clang fp contract(off)
        for (int r = 0; r < 4; ++r) {
            int ci = (r == 0) ? c1 : (r == 1) ? c2 : (r == 2) ? c3 : c4;
            bool act = (cnt > r);
            if (act) {
                const float* crow = cbq + (size_t)ci * D_;
                float A = 0.0f;
                for (int d = 0; d < D_; ++d) A = fmaf(xcol[(size_t)d * N_], crow[d], A);
                float T = S - 2.0f * A;
                float v = T + Hqq[ci];
                if (v < bestv) { bestv = v; besti = ci; }   // ascending ci -> lowest-index ties
            }
        }
    } else {
        // provably-safe slow path (astronomically rare)
#pragma clang fp contract(off)
        bestv = 3.4e38f; besti = 0;
        for (int c = 0; c < C_; ++c) {
            float va = __half2float(drow[c]);
            if (va <= thr) {
                const float* crow = cbq + (size_t)c * D_;
                float A = 0.0f;
                for (int d = 0; d < D_; ++d) A = fmaf(xcol[(size_t)d * N_], crow[d], A);
                float T = S - 2.0f * A;
                float v = T + Hqq[c];
                if (v < bestv) { bestv = v; besti = c; }
            }
        }
    }
    if (valid) codes[(size_t)q * N_ + n] = besti;
}

// ---------------- fused residual update + next-stage S partials + loss partials (verified) ----------------
__global__ __launch_bounds__(256) void k_upd(
        float* __restrict__ res2, const float* __restrict__ cb,
        const int* __restrict__ codes, float* __restrict__ Sp,
        double* __restrict__ part, int q) {
#pragma clang fp contract(off)
    int seg = blockIdx.x / NBLK;
    int nb  = blockIdx.x % NBLK;
    int n = nb * 256 + threadIdx.x;
    float L = 0.0f;
    if (n < N_) {
        int idx = codes[(size_t)q * N_ + n];
        const float* crow = cb + ((size_t)q * C_ + idx) * D_ + seg * 128;
        float* rp = res2 + (size_t)(seg * 128) * N_ + n;
        float r8[8];
#pragma unroll
        for (int j = 0; j < 8; ++j) {
            float r = rp[(size_t)j * N_] - crow[j];
            rp[(size_t)j * N_] = r;
            r8[j] = r * r;
        }
        for (int i = 8; i < 128; i += 8) {
#pragma unroll
            for (int j = 0; j < 8; ++j) {
                float r = rp[(size_t)(i + j) * N_] - crow[i + j];
                rp[(size_t)(i + j) * N_] = r;
                r8[j] = r8[j] + r * r;
            }
        }
        L = ((r8[0] + r8[1]) + (r8[2] + r8[3])) + ((r8[4] + r8[5]) + (r8[6] + r8[7]));
        Sp[(size_t)seg * N_ + n] = L;
    }
    double s = (double)L;
#pragma unroll
    for (int off = 32; off; off >>= 1) s += __shfl_down(s, off, 64);
    __shared__ double sred[4];
    int lane = threadIdx.x & 63, wv = threadIdx.x >> 6;
    if (lane == 0) sred[wv] = s;
    __syncthreads();
    if (threadIdx.x == 0)
        part[(size_t)q * UPDBLK + blockIdx.x] = sred[0] + sred[1] + sred[2] + sred[3];
}

// ---------------- outputs ----------------
__global__ void k_out0(const float* __restrict__ lat, const float* __restrict__ res2,
                       float* __restrict__ out) {
    int bi = blockIdx.x;
    int d = bi & 511, b = bi >> 9;
    const float* lp = lat + (size_t)bi * F_;
    const float* rp = res2 + (size_t)d * N_ + (size_t)b * F_;
    float* op = out + (size_t)bi * F_;
    for (int f = threadIdx.x; f < F_; f += 256) op[f] = lp[f] - rp[f];
}

__global__ void k_codes(const int* __restrict__ codes, float* __restrict__ out1) {
    int bi = blockIdx.x;
    int q = bi & 7, b = bi >> 3;
    for (int f = threadIdx.x; f < F_; f += 256)
        out1[(size_t)bi * F_ + f] = (float)codes[(size_t)q * N_ + (size_t)b * F_ + f];
}

__global__ void k_loss(const double* __restrict__ part, float* __restrict__ out2) {
    double s = 0.0;
    for (int i = threadIdx.x; i < Q_ * UPDBLK; i += 256) s += part[i];
#pragma unroll
    for (int off = 32; off; off >>= 1) s += __shfl_down(s, off, 64);
    __shared__ double red[4];
    int lane = threadIdx.x & 63, wv = threadIdx.x >> 6;
    if (lane == 0) red[wv] = s;
    __syncthreads();
    if (threadIdx.x == 0) {
        double tot = red[0] + red[1] + red[2] + red[3];
        float val = (float)(tot / ((double)Q_ * (double)B_ * (double)D_ * (double)F_));
        out2[0] = val;
        out2[1] = val;
    }
}

extern "C" void kernel_launch(void* const* d_in, const int* in_sizes, int n_in,
                              void* d_out, int out_size, void* d_ws, size_t ws_size,
                              hipStream_t stream) {
    const float* lat = (const float*)d_in[0];   // [16,512,1500] fp32
    const float* cb  = (const float*)d_in[1];   // [8,1024,512]  fp32
    char* ws = (char*)d_ws;
    float*  res2  = (float*)(ws);                       // 49,152,000 B
    __half* Dh    = (__half*)(ws + 49152000);           // 24064*1024*2 = 49,283,072 B
    int*    codes = (int*)   (ws + 98435072);           //    768,000 B
    float*  Hq    = (float*) (ws + 99203072);           //     32,768 B
    float*  Sp    = (float*) (ws + 99235840);           //    384,000 B
    float*  Sn    = (float*) (ws + 99619840);           //     96,000 B
    double* part  = (double*)(ws + 99715840);           //     24,064 B
    float* out = (float*)d_out;

    hipLaunchKernelGGL(k_init,     dim3(B_ * D_), dim3(256), 0, stream, lat, res2);
    hipLaunchKernelGGL(k_cbnormP,  dim3(Q_ * C_ / 256), dim3(256), 0, stream, cb, Hq);
    hipLaunchKernelGGL(k_rownorm4, dim3(NBLK), dim3(256), 0, stream, res2, Sp);
    hipLaunchKernelGGL(k_ssum,     dim3(NBLK), dim3(256), 0, stream, Sp, Sn);

    for (int q = 0; q < Q_; ++q) {
        hipLaunchKernelGGL(k_gemm,   dim3(MPAD / 128, C_ / 128), dim3(256), 0, stream,
                           res2, cb, Hq, Dh, q);
        hipLaunchKernelGGL(k_screen, dim3(NBLK), dim3(256), 0, stream,
                           Dh, res2, cb, Hq, Sn, codes, q);
        hipLaunchKernelGGL(k_upd,    dim3(UPDBLK), dim3(256), 0, stream,
                           res2, cb, codes, Sp, part, q);
        hipLaunchKernelGGL(k_ssum,   dim3(NBLK), dim3(256), 0, stream, Sp, Sn);
    }

    hipLaunchKernelGGL(k_out0,  dim3(B_ * D_), dim3(256), 0, stream, lat, res2, out);
    hipLaunchKernelGGL(k_codes, dim3(B_ * Q_), dim3(256), 0, stream, codes, out + 12288000);
    hipLaunchKernelGGL(k_loss,  dim3(1), dim3(256), 0, stream, part, out + 12480000);
}

// Round 9
// 4188.154 us; speedup vs baseline: 5.5617x; 2.8154x over previous
//
#include <hip/hip_runtime.h>
#include <hip/hip_fp16.h>

// ResidualVectorQuantizer: B=16, D=512, F=1500, Q=8, C=1024
#define B_ 16
#define D_ 512
#define F_ 1500
#define N_ (B_*F_)   // 24000
#define Q_ 8
#define C_ 1024

constexpr int NBLK  = (N_ + 255) / 256;   // 94
constexpr int UPDBLK = 4 * NBLK;          // 376
constexpr int MPAD = 24064;               // padded rows for GEMM (188*128)
constexpr int FB_  = (F_ + 31) / 32;      // 47 f-tiles

typedef __attribute__((ext_vector_type(8))) short bf16x8;
typedef __attribute__((ext_vector_type(4))) short bf16x4;
typedef __attribute__((ext_vector_type(4))) float f32x4;
typedef __attribute__((ext_vector_type(8))) unsigned short u16x8;

__device__ __forceinline__ short f2bf(float f) {
    unsigned u = __float_as_uint(f);
    u += 0x7FFFu + ((u >> 16) & 1u);
    return (short)(u >> 16);
}
__device__ __forceinline__ float bf2f(short h) {
    return __uint_as_float(((unsigned)(unsigned short)h) << 16);
}
__device__ __forceinline__ float h2f(unsigned short u) {
    __half_raw r; r.x = u; return __half2float(__half(r));
}

// ---------------- init: resT[b*F+f][d] = lat[b][d][f] (32x32 LDS transpose) ----------------
__global__ void k_initT(const float* __restrict__ lat, float* __restrict__ resT) {
    __shared__ float tile[32][33];
    int bi = blockIdx.x;                 // ((b*16)+db)*47 + fb
    int fb = bi % FB_, rem = bi / FB_;
    int db = rem & 15, b = rem >> 4;
    int tx = threadIdx.x & 31, ty = threadIdx.x >> 5;
    int f0 = fb * 32, d0 = db * 32;
    bool fok = (f0 + tx) < F_;
    for (int i = ty; i < 32; i += 8)
        if (fok) tile[i][tx] = lat[((size_t)b * D_ + d0 + i) * F_ + f0 + tx];
    __syncthreads();
    for (int i = ty; i < 32; i += 8) {
        int f = f0 + i;
        if (f < F_) resT[((size_t)(b * F_ + f)) * D_ + d0 + tx] = tile[tx][i];
    }
}

// ---------------- H[q*C+c] = np.sum(cb*cb, axis=1), numpy pairwise fp32 (verified) ----------------
__global__ void k_cbnormP(const float* __restrict__ cb, float* __restrict__ Hq) {
#pragma clang fp contract(off)
    int wid = blockIdx.x * 256 + threadIdx.x;
    const float* p = cb + (size_t)wid * D_;
    float L[4];
#pragma unroll
    for (int l = 0; l < 4; ++l) {
        const float* pl = p + l * 128;
        float r[8];
#pragma unroll
        for (int j = 0; j < 8; ++j) { float x = pl[j]; r[j] = x * x; }
        for (int i = 8; i < 128; i += 8) {
#pragma unroll
            for (int j = 0; j < 8; ++j) { float x = pl[i + j]; r[j] = r[j] + x * x; }
        }
        L[l] = ((r[0] + r[1]) + (r[2] + r[3])) + ((r[4] + r[5]) + (r[6] + r[7]));
    }
    Hq[wid] = (L[0] + L[1]) + (L[2] + L[3]);
}

// ---------------- initial S partials (pairwise leaves of 128) (verified chain) ----------------
__global__ void k_rownorm4(const float* __restrict__ resT, float* __restrict__ Sp) {
#pragma clang fp contract(off)
    int n = blockIdx.x * 256 + threadIdx.x;
    if (n >= N_) return;
#pragma unroll
    for (int l = 0; l < 4; ++l) {
        const float* p = resT + (size_t)n * D_ + l * 128;
        float r[8];
#pragma unroll
        for (int j = 0; j < 8; ++j) { float x = p[j]; r[j] = x * x; }
        for (int i = 8; i < 128; i += 8) {
#pragma unroll
            for (int j = 0; j < 8; ++j) { float x = p[i + j]; r[j] = r[j] + x * x; }
        }
        Sp[(size_t)l * N_ + n] = ((r[0] + r[1]) + (r[2] + r[3])) + ((r[4] + r[5]) + (r[6] + r[7]));
    }
}

// ---------------- Sn[n] = pairwise top-join (verified) ----------------
__global__ void k_ssum(const float* __restrict__ Sp, float* __restrict__ Sn) {
#pragma clang fp contract(off)
    int n = blockIdx.x * 256 + threadIdx.x;
    if (n >= N_) return;
    Sn[n] = (Sp[n] + Sp[N_ + n]) + (Sp[2 * N_ + n] + Sp[3 * N_ + n]);
}

// ---------------- MFMA screen GEMM: Dh[n][c] = fp16(H[c] - 2*A_mfma) (verified) ----------------
#define LSTR 80
__global__ __launch_bounds__(256) void k_gemm(
        const float* __restrict__ resT, const float* __restrict__ cb,
        const float* __restrict__ Hq, __half* __restrict__ Dh, int q) {
    __shared__ short xh[128 * LSTR], xl[128 * LSTR];
    __shared__ short ch[128 * LSTR], cl[128 * LSTR];
    const int t = threadIdx.x;
    const int n0 = blockIdx.x * 128;
    const int c0 = blockIdx.y * 128;
    const int l = t & 63, w = t >> 6;
    const int wr = w >> 1, wc = w & 1;
    const float* cbq = cb + (size_t)q * ((size_t)C_ * D_);

    f32x4 acc[4][4];
#pragma unroll
    for (int i = 0; i < 4; ++i)
#pragma unroll
        for (int j = 0; j < 4; ++j) { acc[i][j][0]=0.f; acc[i][j][1]=0.f; acc[i][j][2]=0.f; acc[i][j][3]=0.f; }

    for (int kc = 0; kc < D_; kc += 64) {
        __syncthreads();
        // stage X: 128 n-rows x 64 d from resT (contiguous), split h/l
#pragma unroll
        for (int p = 0; p < 4; ++p) {
            int g = p * 256 + t;
            int d8 = g & 7, n = g >> 3;
            const float* xr = resT + (size_t)(n0 + n) * D_ + kc + d8 * 8;
            bf16x8 hv, lv;
#pragma unroll
            for (int i = 0; i < 8; ++i) {
                float v = xr[i];
                short h = f2bf(v);
                hv[i] = h;
                lv[i] = f2bf(v - bf2f(h));
            }
            *(bf16x8*)(&xh[n * LSTR + d8 * 8]) = hv;
            *(bf16x8*)(&xl[n * LSTR + d8 * 8]) = lv;
        }
        // stage C: 128 c-rows x 64 d from cb, split h/l
#pragma unroll
        for (int p = 0; p < 8; ++p) {
            int g = p * 256 + t;
            int cr = g >> 4, d4 = (g & 15) * 4;
            float4 v = *(const float4*)(cbq + (size_t)(c0 + cr) * D_ + kc + d4);
            bf16x4 hv, lv;
            float vv[4] = {v.x, v.y, v.z, v.w};
#pragma unroll
            for (int i = 0; i < 4; ++i) {
                short h = f2bf(vv[i]);
                hv[i] = h;
                lv[i] = f2bf(vv[i] - bf2f(h));
            }
            *(bf16x4*)(&ch[cr * LSTR + d4]) = hv;
            *(bf16x4*)(&cl[cr * LSTR + d4]) = lv;
        }
        __syncthreads();

#pragma unroll
        for (int kf = 0; kf < 2; ++kf) {
            const int ko = kf * 32 + (l >> 4) * 8;
            bf16x8 ah[4], al[4], bh[4], bl[4];
#pragma unroll
            for (int i = 0; i < 4; ++i) {
                int xr2 = wr * 64 + i * 16 + (l & 15);
                ah[i] = *(const bf16x8*)(&xh[xr2 * LSTR + ko]);
                al[i] = *(const bf16x8*)(&xl[xr2 * LSTR + ko]);
                int cr = wc * 64 + i * 16 + (l & 15);
                bh[i] = *(const bf16x8*)(&ch[cr * LSTR + ko]);
                bl[i] = *(const bf16x8*)(&cl[cr * LSTR + ko]);
            }
#pragma unroll
            for (int i = 0; i < 4; ++i)
#pragma unroll
                for (int j = 0; j < 4; ++j) {
                    acc[i][j] = __builtin_amdgcn_mfma_f32_16x16x32_bf16(ah[i], bh[j], acc[i][j], 0, 0, 0);
                    acc[i][j] = __builtin_amdgcn_mfma_f32_16x16x32_bf16(ah[i], bl[j], acc[i][j], 0, 0, 0);
                    acc[i][j] = __builtin_amdgcn_mfma_f32_16x16x32_bf16(al[i], bh[j], acc[i][j], 0, 0, 0);
                }
        }
    }

    const float* Hqq = Hq + (size_t)q * C_;
#pragma unroll
    for (int i = 0; i < 4; ++i)
#pragma unroll
        for (int j = 0; j < 4; ++j) {
            int c = c0 + wc * 64 + j * 16 + (l & 15);
            float h = Hqq[c];
#pragma unroll
            for (int r = 0; r < 4; ++r) {
                int n = n0 + wr * 64 + i * 16 + (l >> 4) * 4 + r;
                Dh[(size_t)n * C_ + c] = __float2half(h - 2.0f * acc[i][j][r]);
            }
        }
}

// ---------------- screen: wave per row, vectorized scan + parallel exact rescore ----------------
__global__ __launch_bounds__(256) void k_screen(
        const __half* __restrict__ Dh, const float* __restrict__ resT,
        const float* __restrict__ cb, const float* __restrict__ Hq,
        const float* __restrict__ Sn, int* __restrict__ codes, int q) {
#pragma clang fp contract(off)
    __shared__ int scnt[4];
    __shared__ int scand[4][8];
    const int w = threadIdx.x >> 6, lane = threadIdx.x & 63;
    const int n = blockIdx.x * 4 + w;           // grid=6000 -> always < N_
    const __half* drow = Dh + (size_t)n * C_;
    const float* cbq = cb + (size_t)q * ((size_t)C_ * D_);
    const float* Hqq = Hq + (size_t)q * C_;

    // vector-load 16 halfs per lane (row fully covered, coalesced)
    u16x8 va = *(const u16x8*)((const unsigned short*)drow + lane * 16);
    u16x8 vb = *(const u16x8*)((const unsigned short*)drow + lane * 16 + 8);
    float v[16];
#pragma unroll
    for (int i = 0; i < 8; ++i) { v[i] = h2f(va[i]); v[8 + i] = h2f(vb[i]); }

    float m = v[0];
#pragma unroll
    for (int i = 1; i < 16; ++i) m = fminf(m, v[i]);
#pragma unroll
    for (int off = 32; off; off >>= 1) m = fminf(m, __shfl_xor(m, off, 64));
    const float thr = m + 4e-3f;

    if (lane == 0) scnt[w] = 0;
    __syncthreads();
#pragma unroll
    for (int k = 0; k < 16; ++k) {
        if (v[k] <= thr) {
            int i = atomicAdd(&scnt[w], 1);
            if (i < 8) scand[w][i] = lane * 16 + k;
        }
    }
    __syncthreads();
    const int cnt = scnt[w];                   // wave-uniform
    const float S = Sn[n];

    int bi_ = 0x7fffffff;
    if (cnt <= 8) {
        float mv2 = 3.4e38f; int mi = 0x7fffffff;
        if (lane < cnt) {
            int ci = scand[w][lane];
            const float* xr = resT + (size_t)n * D_;
            const float* cr = cbq + (size_t)ci * D_;
            float A = 0.0f;
#pragma unroll 8
            for (int d = 0; d < D_; ++d) A = fmaf(xr[d], cr[d], A);
            float T = S - 2.0f * A;
            mv2 = T + Hqq[ci];
            mi = ci;
        }
#pragma unroll
        for (int off = 32; off; off >>= 1) {
            float ov = __shfl_xor(mv2, off, 64);
            int   oi = __shfl_xor(mi,  off, 64);
            if (ov < mv2 || (ov == mv2 && oi < mi)) { mv2 = ov; mi = oi; }
        }
        bi_ = mi;
    } else {
        // safe fallback (astronomically rare): serial exact scan of all candidates
        if (lane == 0) {
            float bv = 3.4e38f; bi_ = 0;
            for (int c = 0; c < C_; ++c) {
                float vap = h2f(((const unsigned short*)drow)[c]);
                if (vap <= thr) {
                    const float* xr = resT + (size_t)n * D_;
                    const float* cr = cbq + (size_t)c * D_;
                    float A = 0.0f;
                    for (int d = 0; d < D_; ++d) A = fmaf(xr[d], cr[d], A);
                    float T = S - 2.0f * A;
                    float val = T + Hqq[c];
                    if (val < bv) { bv = val; bi_ = c; }
                }
            }
        }
    }
    if (lane == 0) codes[(size_t)q * N_ + n] = bi_;
}

// ---------------- fused residual update + next-stage S partials + loss partials (verified) ----------------
__global__ __launch_bounds__(256) void k_upd(
        float* __restrict__ resT, const float* __restrict__ cb,
        const int* __restrict__ codes, float* __restrict__ Sp,
        double* __restrict__ part, int q) {
#pragma clang fp contract(off)
    int seg = blockIdx.x / NBLK;
    int nb  = blockIdx.x % NBLK;
    int n = nb * 256 + threadIdx.x;
    float L = 0.0f;
    if (n < N_) {
        int idx = codes[(size_t)q * N_ + n];
        const float* crow = cb + ((size_t)q * C_ + idx) * D_ + seg * 128;
        float* rp = resT + (size_t)n * D_ + seg * 128;
        float r8[8];
#pragma unroll
        for (int j = 0; j < 8; ++j) {
            float r = rp[j] - crow[j];
            rp[j] = r;
            r8[j] = r * r;
        }
        for (int i = 8; i < 128; i += 8) {
#pragma unroll
            for (int j = 0; j < 8; ++j) {
                float r = rp[i + j] - crow[i + j];
                rp[i + j] = r;
                r8[j] = r8[j] + r * r;
            }
        }
        L = ((r8[0] + r8[1]) + (r8[2] + r8[3])) + ((r8[4] + r8[5]) + (r8[6] + r8[7]));
        Sp[(size_t)seg * N_ + n] = L;
    }
    double s = (double)L;
#pragma unroll
    for (int off = 32; off; off >>= 1) s += __shfl_down(s, off, 64);
    __shared__ double sred[4];
    int lane = threadIdx.x & 63, wv = threadIdx.x >> 6;
    if (lane == 0) sred[wv] = s;
    __syncthreads();
    if (threadIdx.x == 0)
        part[(size_t)q * UPDBLK + blockIdx.x] = sred[0] + sred[1] + sred[2] + sred[3];
}

// ---------------- out0: out[b][d][f] = lat - resT (32x32 LDS transpose) ----------------
__global__ void k_out0T(const float* __restrict__ lat, const float* __restrict__ resT,
                        float* __restrict__ out) {
    __shared__ float tile[32][33];
    int bi = blockIdx.x;
    int fb = bi % FB_, rem = bi / FB_;
    int db = rem & 15, b = rem >> 4;
    int tx = threadIdx.x & 31, ty = threadIdx.x >> 5;
    int f0 = fb * 32, d0 = db * 32;
    for (int i = ty; i < 32; i += 8) {
        int f = f0 + i;
        if (f < F_) tile[i][tx] = resT[((size_t)(b * F_ + f)) * D_ + d0 + tx];
    }
    __syncthreads();
    bool fok = (f0 + tx) < F_;
    for (int i = ty; i < 32; i += 8) {
        if (fok) {
            size_t o = ((size_t)b * D_ + d0 + i) * F_ + f0 + tx;
            out[o] = lat[o] - tile[tx][i];
        }
    }
}

__global__ void k_codes(const int* __restrict__ codes, float* __restrict__ out1) {
    int bi = blockIdx.x;
    int q = bi & 7, b = bi >> 3;
    for (int f = threadIdx.x; f < F_; f += 256)
        out1[(size_t)bi * F_ + f] = (float)codes[(size_t)q * N_ + (size_t)b * F_ + f];
}

__global__ void k_loss(const double* __restrict__ part, float* __restrict__ out2) {
    double s = 0.0;
    for (int i = threadIdx.x; i < Q_ * UPDBLK; i += 256) s += part[i];
#pragma unroll
    for (int off = 32; off; off >>= 1) s += __shfl_down(s, off, 64);
    __shared__ double red[4];
    int lane = threadIdx.x & 63, wv = threadIdx.x >> 6;
    if (lane == 0) red[wv] = s;
    __syncthreads();
    if (threadIdx.x == 0) {
        double tot = red[0] + red[1] + red[2] + red[3];
        float val = (float)(tot / ((double)Q_ * (double)B_ * (double)D_ * (double)F_));
        out2[0] = val;
        out2[1] = val;
    }
}

extern "C" void kernel_launch(void* const* d_in, const int* in_sizes, int n_in,
                              void* d_out, int out_size, void* d_ws, size_t ws_size,
                              hipStream_t stream) {
    const float* lat = (const float*)d_in[0];   // [16,512,1500] fp32
    const float* cb  = (const float*)d_in[1];   // [8,1024,512]  fp32
    char* ws = (char*)d_ws;
    float*  resT  = (float*)(ws);                        // MPAD*512*4 = 49,283,072 B
    __half* Dh    = (__half*)(ws + 49283072);            // MPAD*1024*2 = 49,283,072 B
    int*    codes = (int*)   (ws + 98566144);            //    768,000 B
    float*  Hq    = (float*) (ws + 99334144);            //     32,768 B
    float*  Sp    = (float*) (ws + 99366912);            //    384,000 B
    float*  Sn    = (float*) (ws + 99750912);            //     96,000 B
    double* part  = (double*)(ws + 99846912);            //     24,064 B
    float* out = (float*)d_out;

    hipLaunchKernelGGL(k_initT,    dim3(B_ * 16 * FB_), dim3(256), 0, stream, lat, resT);
    hipLaunchKernelGGL(k_cbnormP,  dim3(Q_ * C_ / 256), dim3(256), 0, stream, cb, Hq);
    hipLaunchKernelGGL(k_rownorm4, dim3(NBLK), dim3(256), 0, stream, resT, Sp);
    hipLaunchKernelGGL(k_ssum,     dim3(NBLK), dim3(256), 0, stream, Sp, Sn);

    for (int q = 0; q < Q_; ++q) {
        hipLaunchKernelGGL(k_gemm,   dim3(MPAD / 128, C_ / 128), dim3(256), 0, stream,
                           resT, cb, Hq, Dh, q);
        hipLaunchKernelGGL(k_screen, dim3(N_ / 4), dim3(256), 0, stream,
                           Dh, resT, cb, Hq, Sn, codes, q);
        hipLaunchKernelGGL(k_upd,    dim3(UPDBLK), dim3(256), 0, stream,
                           resT, cb, codes, Sp, part, q);
        hipLaunchKernelGGL(k_ssum,   dim3(NBLK), dim3(256), 0, stream, Sp, Sn);
    }

    hipLaunchKernelGGL(k_out0T, dim3(B_ * 16 * FB_), dim3(256), 0, stream, lat, resT, out);
    hipLaunchKernelGGL(k_codes, dim3(B_ * Q_), dim3(256), 0, stream, codes, out + 12288000);
    hipLaunchKernelGGL(k_loss,  dim3(1), dim3(256), 0, stream, part, out + 12480000);
}

// Round 10
// 3673.056 us; speedup vs baseline: 6.3417x; 1.1402x over previous
//
#include <hip/hip_runtime.h>
#include <hip/hip_fp16.h>

// ResidualVectorQuantizer: B=16, D=512, F=1500, Q=8, C=1024
#define B_ 16
#define D_ 512
#define F_ 1500
#define N_ (B_*F_)   // 24000
#define Q_ 8
#define C_ 1024

constexpr int NBLK  = (N_ + 255) / 256;   // 94
constexpr int UPDBLK = 4 * NBLK;          // 376
constexpr int MPAD = 24064;               // padded rows (188*128)
constexpr int FB_  = (F_ + 31) / 32;      // 47
constexpr int CAP_ = 192000;              // candidate list capacity

typedef __attribute__((ext_vector_type(8))) short bf16x8;
typedef __attribute__((ext_vector_type(4))) float f32x4;

__device__ __forceinline__ short f2bf(float f) {
    unsigned u = __float_as_uint(f);
    u += 0x7FFFu + ((u >> 16) & 1u);
    return (short)(u >> 16);
}
__device__ __forceinline__ float h2f(unsigned short u) {
    __half_raw r; r.x = u; return __half2float(__half(r));
}
__device__ __forceinline__ unsigned short f2h(float f) {
    __half h = __float2half(f);
    return __half_as_ushort(h);
}

// ---------------- init: resT/resbf[b*F+f][d] = lat[b][d][f] ----------------
__global__ void k_initT(const float* __restrict__ lat, float* __restrict__ resT,
                        short* __restrict__ resbf) {
    __shared__ float tile[32][33];
    int bi = blockIdx.x;
    int fb = bi % FB_, rem = bi / FB_;
    int db = rem & 15, b = rem >> 4;
    int tx = threadIdx.x & 31, ty = threadIdx.x >> 5;
    int f0 = fb * 32, d0 = db * 32;
    bool fok = (f0 + tx) < F_;
    for (int i = ty; i < 32; i += 8)
        if (fok) tile[i][tx] = lat[((size_t)b * D_ + d0 + i) * F_ + f0 + tx];
    __syncthreads();
    for (int i = ty; i < 32; i += 8) {
        int f = f0 + i;
        if (f < F_) {
            float v = tile[tx][i];
            size_t o = ((size_t)(b * F_ + f)) * D_ + d0 + tx;
            resT[o] = v;
            resbf[o] = f2bf(v);
        }
    }
}

// ---------------- cbh = bf16(cb), built once ----------------
__global__ void k_cbh(const float* __restrict__ cb, short* __restrict__ cbh) {
    size_t base = ((size_t)blockIdx.x * 256 + threadIdx.x) * 8;
    float4 a = *(const float4*)(cb + base);
    float4 b = *(const float4*)(cb + base + 4);
    bf16x8 o;
    o[0]=f2bf(a.x); o[1]=f2bf(a.y); o[2]=f2bf(a.z); o[3]=f2bf(a.w);
    o[4]=f2bf(b.x); o[5]=f2bf(b.y); o[6]=f2bf(b.z); o[7]=f2bf(b.w);
    *(bf16x8*)(cbh + base) = o;
}

// ---------------- H[q*C+c] = np.sum(cb*cb, axis=1), numpy pairwise fp32 (verified) ----------------
__global__ void k_cbnormP(const float* __restrict__ cb, float* __restrict__ Hq) {
#pragma clang fp contract(off)
    int wid = blockIdx.x * 256 + threadIdx.x;
    const float* p = cb + (size_t)wid * D_;
    float L[4];
#pragma unroll
    for (int l = 0; l < 4; ++l) {
        const float* pl = p + l * 128;
        float r[8];
#pragma unroll
        for (int j = 0; j < 8; ++j) { float x = pl[j]; r[j] = x * x; }
        for (int i = 8; i < 128; i += 8) {
#pragma unroll
            for (int j = 0; j < 8; ++j) { float x = pl[i + j]; r[j] = r[j] + x * x; }
        }
        L[l] = ((r[0] + r[1]) + (r[2] + r[3])) + ((r[4] + r[5]) + (r[6] + r[7]));
    }
    Hq[wid] = (L[0] + L[1]) + (L[2] + L[3]);
}

// ---------------- initial S partials (verified chain) ----------------
__global__ void k_rownorm4(const float* __restrict__ resT, float* __restrict__ Sp) {
#pragma clang fp contract(off)
    int n = blockIdx.x * 256 + threadIdx.x;
    if (n >= N_) return;
#pragma unroll
    for (int l = 0; l < 4; ++l) {
        const float* p = resT + (size_t)n * D_ + l * 128;
        float r[8];
#pragma unroll
        for (int j = 0; j < 8; ++j) { float x = p[j]; r[j] = x * x; }
        for (int i = 8; i < 128; i += 8) {
#pragma unroll
            for (int j = 0; j < 8; ++j) { float x = p[i + j]; r[j] = r[j] + x * x; }
        }
        Sp[(size_t)l * N_ + n] = ((r[0] + r[1]) + (r[2] + r[3])) + ((r[4] + r[5]) + (r[6] + r[7]));
    }
}

// ---------------- Sn[n] = pairwise top-join (verified) ----------------
__global__ void k_ssum(const float* __restrict__ Sp, float* __restrict__ Sn) {
#pragma clang fp contract(off)
    int n = blockIdx.x * 256 + threadIdx.x;
    if (n >= N_) return;
    Sn[n] = (Sp[n] + Sp[N_ + n]) + (Sp[2 * N_ + n] + Sp[3 * N_ + n]);
}

// ---------------- bf16 MFMA screen GEMM: emits per-row-block candidate slots ----------------
#define LSTR 80
__global__ __launch_bounds__(256) void k_gemm(
        const short* __restrict__ resbf, const short* __restrict__ cbh,
        const float* __restrict__ Hq, float* __restrict__ Dmin,
        unsigned* __restrict__ candBuf, unsigned* __restrict__ cnt8,
        int* __restrict__ gcount, int q) {
    __shared__ short xh[128 * LSTR];
    __shared__ short ch[128 * LSTR];
    __shared__ float smin[128][2];
    __shared__ float bminL[128];
    __shared__ unsigned lcnt[128];
    __shared__ unsigned slots[128][8];

    const int t = threadIdx.x;
    if (blockIdx.x == 0 && blockIdx.y == 0 && t == 0) *gcount = 0;
    const int n0 = blockIdx.x * 128;
    const int cby = blockIdx.y;
    const int c0 = cby * 128;
    const int l = t & 63, w = t >> 6;
    const int wr = w >> 1, wc = w & 1;
    const short* cbhq = cbh + ((size_t)q * C_) * D_;

    f32x4 acc[4][4];
#pragma unroll
    for (int i = 0; i < 4; ++i)
#pragma unroll
        for (int j = 0; j < 4; ++j) { acc[i][j][0]=0.f; acc[i][j][1]=0.f; acc[i][j][2]=0.f; acc[i][j][3]=0.f; }

    for (int kc = 0; kc < D_; kc += 64) {
        __syncthreads();
#pragma unroll
        for (int p = 0; p < 4; ++p) {
            int idx = p * 256 + t;
            int nn = idx >> 3, d8 = idx & 7;
            *(bf16x8*)(&xh[nn * LSTR + d8 * 8]) =
                *(const bf16x8*)(resbf + (size_t)(n0 + nn) * D_ + kc + d8 * 8);
        }
#pragma unroll
        for (int p = 0; p < 4; ++p) {
            int idx = p * 256 + t;
            int cr = idx >> 3, d8 = idx & 7;
            *(bf16x8*)(&ch[cr * LSTR + d8 * 8]) =
                *(const bf16x8*)(cbhq + (size_t)(c0 + cr) * D_ + kc + d8 * 8);
        }
        __syncthreads();

#pragma unroll
        for (int kf = 0; kf < 2; ++kf) {
            const int ko = kf * 32 + (l >> 4) * 8;
            bf16x8 ah[4], bh[4];
#pragma unroll
            for (int i = 0; i < 4; ++i) {
                ah[i] = *(const bf16x8*)(&xh[(wr * 64 + i * 16 + (l & 15)) * LSTR + ko]);
                bh[i] = *(const bf16x8*)(&ch[(wc * 64 + i * 16 + (l & 15)) * LSTR + ko]);
            }
#pragma unroll
            for (int i = 0; i < 4; ++i)
#pragma unroll
                for (int j = 0; j < 4; ++j)
                    acc[i][j] = __builtin_amdgcn_mfma_f32_16x16x32_bf16(ah[i], bh[j], acc[i][j], 0, 0, 0);
        }
    }

    // ---- epilogue: per-row block-min + candidate slots ----
    const float* Hqq = Hq + (size_t)q * C_;
    float hv[4];
#pragma unroll
    for (int j = 0; j < 4; ++j) hv[j] = Hqq[c0 + wc * 64 + j * 16 + (l & 15)];

    // pass 1: row minima
#pragma unroll
    for (int i = 0; i < 4; ++i)
#pragma unroll
        for (int r = 0; r < 4; ++r) {
            float vm = hv[0] - 2.0f * acc[i][0][r];
#pragma unroll
            for (int j = 1; j < 4; ++j) vm = fminf(vm, hv[j] - 2.0f * acc[i][j][r]);
            vm = fminf(vm, __shfl_xor(vm, 1, 64));
            vm = fminf(vm, __shfl_xor(vm, 2, 64));
            vm = fminf(vm, __shfl_xor(vm, 4, 64));
            vm = fminf(vm, __shfl_xor(vm, 8, 64));
            if ((l & 15) == 0) smin[wr * 64 + i * 16 + (l >> 4) * 4 + r][wc] = vm;
        }
    __syncthreads();
    if (t < 128) {
        bminL[t] = fminf(smin[t][0], smin[t][1]);
        lcnt[t] = 0;
    }
    __syncthreads();
    // pass 2: emit
#pragma unroll
    for (int i = 0; i < 4; ++i)
#pragma unroll
        for (int j = 0; j < 4; ++j)
#pragma unroll
            for (int r = 0; r < 4; ++r) {
                int row = wr * 64 + i * 16 + (l >> 4) * 4 + r;
                float v = hv[j] - 2.0f * acc[i][j][r];
                if (v <= bminL[row] + 4e-3f) {
                    unsigned pos = atomicAdd(&lcnt[row], 1u);
                    if (pos < 8) {
                        unsigned c = (unsigned)(c0 + wc * 64 + j * 16 + (l & 15));
                        slots[row][pos] = ((unsigned)f2h(v) << 16) | c;
                    }
                }
            }
    __syncthreads();
    if (t < 128) {
        int n = n0 + t;
        Dmin[(size_t)n * 8 + cby] = bminL[t];
        unsigned cnt = lcnt[t];
        cnt8[(size_t)n * 8 + cby] = cnt;
        unsigned m = cnt < 8u ? cnt : 8u;
        for (unsigned s = 0; s < m; ++s)
            candBuf[((size_t)n * 8 + cby) * 8 + s] = slots[t][s];
    }
}

// ---------------- collect: thr from block-mins, resolve tot==1, emit rest ----------------
__global__ __launch_bounds__(256) void k_collect(
        const float* __restrict__ Dmin, const unsigned* __restrict__ candBuf,
        const unsigned* __restrict__ cnt8, const float* __restrict__ resT,
        const float* __restrict__ cb, const float* __restrict__ Hq,
        const float* __restrict__ Sn, int* __restrict__ codes,
        unsigned* __restrict__ cand, int* __restrict__ gcount,
        unsigned long long* __restrict__ rkey, int q) {
#pragma clang fp contract(off)
    const int w = threadIdx.x >> 6, lane = threadIdx.x & 63;
    const int n = blockIdx.x * 4 + w;

    float m = 3.4e38f;
    if (lane < 8) m = Dmin[(size_t)n * 8 + lane];
    m = fminf(m, __shfl_xor(m, 4, 64));
    m = fminf(m, __shfl_xor(m, 2, 64));
    m = fminf(m, __shfl_xor(m, 1, 64));
    m = __shfl(m, 0, 64);
    const float thr = m + 4e-3f + 1e-4f;

    unsigned cl = (lane < 8) ? cnt8[(size_t)n * 8 + lane] : 0u;
    bool ovf = __any(cl > 8u);

    if (!ovf) {
        int blk = lane >> 3, s = lane & 7;
        unsigned cb8 = cnt8[(size_t)n * 8 + blk];
        bool has = false; int myc = -1;
        if ((unsigned)s < cb8) {
            unsigned e = candBuf[((size_t)n * 8 + blk) * 8 + s];
            float vh = h2f((unsigned short)(e >> 16));
            if (vh <= thr) { has = true; myc = (int)(e & 0x3FFu); }
        }
        unsigned long long mask = __ballot(has);
        int tot = __popcll(mask);
        if (tot == 1) {
            if (has) codes[(size_t)q * N_ + n] = myc;
            return;
        }
        int pre = __popcll(mask & ((1ull << lane) - 1ull));
        int base = 0;
        if (lane == 0) base = atomicAdd(gcount, tot);
        base = __shfl(base, 0, 64);
        if (base + tot <= CAP_) {
            if (lane == 0) { rkey[n] = ~0ull; codes[(size_t)q * N_ + n] = -1; }
            if (has) cand[base + pre] = ((unsigned)n << 10) | (unsigned)myc;
            return;
        }
        ovf = true;
    }
    // exact full-row fallback (rare): wave-parallel over c, verified chain per c
    {
        const float S = Sn[n];
        const float* xr = resT + (size_t)n * D_;
        const float* cbq = cb + (size_t)q * ((size_t)C_ * D_);
        const float* Hqq = Hq + (size_t)q * C_;
        float bv = 3.4e38f; int bc = 0x7fffffff;
        for (int rep = 0; rep < 16; ++rep) {
            int c = lane + rep * 64;
            const float* cr = cbq + (size_t)c * D_;
            float A = 0.0f;
            for (int d = 0; d < D_; ++d) A = fmaf(xr[d], cr[d], A);
            float v = (S - 2.0f * A) + Hqq[c];
            if (v < bv || (v == bv && c < bc)) { bv = v; bc = c; }
        }
        for (int off = 32; off; off >>= 1) {
            float ov = __shfl_xor(bv, off, 64);
            int oc = __shfl_xor(bc, off, 64);
            if (ov < bv || (ov == bv && oc < bc)) { bv = ov; bc = oc; }
        }
        if (lane == 0) codes[(size_t)q * N_ + n] = bc;
    }
}

// ---------------- rescore: exact chain per candidate, lexicographic atomicMin ----------------
__global__ __launch_bounds__(256) void k_rescore(
        const unsigned* __restrict__ cand, const int* __restrict__ gcount,
        const float* __restrict__ resT, const float* __restrict__ cb,
        const float* __restrict__ Hq, const float* __restrict__ Sn,
        unsigned long long* __restrict__ rkey, int q) {
#pragma clang fp contract(off)
    int tid = blockIdx.x * 256 + threadIdx.x;
    int cnt = *gcount; if (cnt > CAP_) cnt = CAP_;
    if (tid >= cnt) return;
    unsigned e = cand[tid];
    int n = (int)(e >> 10), c = (int)(e & 0x3FFu);
    const float* xr = resT + (size_t)n * D_;
    const float* cr = cb + ((size_t)q * C_ + c) * D_;
    float A = 0.0f;
#pragma unroll 8
    for (int d = 0; d < D_; ++d) A = fmaf(xr[d], cr[d], A);
    float v = (Sn[n] - 2.0f * A) + Hq[(size_t)q * C_ + c];
    unsigned long long key = ((unsigned long long)__float_as_uint(v) << 32) | (unsigned)c;
    atomicMin(&rkey[n], key);
}

// ---------------- fused residual update + bf16 shadow + S partials + loss (verified) ----------------
__global__ __launch_bounds__(256) void k_upd(
        float* __restrict__ resT, short* __restrict__ resbf,
        const float* __restrict__ cb, int* __restrict__ codes,
        const unsigned long long* __restrict__ rkey,
        float* __restrict__ Sp, double* __restrict__ part, int q) {
#pragma clang fp contract(off)
    int seg = blockIdx.x / NBLK;
    int nb  = blockIdx.x % NBLK;
    int n = nb * 256 + threadIdx.x;
    float L = 0.0f;
    if (n < N_) {
        int idx = codes[(size_t)q * N_ + n];
        if (idx < 0) idx = (int)(rkey[n] & 0x3FFull);
        if (seg == 0) codes[(size_t)q * N_ + n] = idx;   // benign same-value race
        const float* crow = cb + ((size_t)q * C_ + idx) * D_ + seg * 128;
        float* rp = resT + (size_t)n * D_ + seg * 128;
        short* rb = resbf + (size_t)n * D_ + seg * 128;
        float r8[8];
#pragma unroll
        for (int j = 0; j < 8; ++j) {
            float r = rp[j] - crow[j];
            rp[j] = r; rb[j] = f2bf(r);
            r8[j] = r * r;
        }
        for (int i = 8; i < 128; i += 8) {
#pragma unroll
            for (int j = 0; j < 8; ++j) {
                float r = rp[i + j] - crow[i + j];
                rp[i + j] = r; rb[i + j] = f2bf(r);
                r8[j] = r8[j] + r * r;
            }
        }
        L = ((r8[0] + r8[1]) + (r8[2] + r8[3])) + ((r8[4] + r8[5]) + (r8[6] + r8[7]));
        Sp[(size_t)seg * N_ + n] = L;
    }
    double s = (double)L;
#pragma unroll
    for (int off = 32; off; off >>= 1) s += __shfl_down(s, off, 64);
    __shared__ double sred[4];
    int lane = threadIdx.x & 63, wv = threadIdx.x >> 6;
    if (lane == 0) sred[wv] = s;
    __syncthreads();
    if (threadIdx.x == 0)
        part[(size_t)q * UPDBLK + blockIdx.x] = sred[0] + sred[1] + sred[2] + sred[3];
}

// ---------------- outputs ----------------
__global__ void k_out0T(const float* __restrict__ lat, const float* __restrict__ resT,
                        float* __restrict__ out) {
    __shared__ float tile[32][33];
    int bi = blockIdx.x;
    int fb = bi % FB_, rem = bi / FB_;
    int db = rem & 15, b = rem >> 4;
    int tx = threadIdx.x & 31, ty = threadIdx.x >> 5;
    int f0 = fb * 32, d0 = db * 32;
    for (int i = ty; i < 32; i += 8) {
        int f = f0 + i;
        if (f < F_) tile[i][tx] = resT[((size_t)(b * F_ + f)) * D_ + d0 + tx];
    }
    __syncthreads();
    bool fok = (f0 + tx) < F_;
    for (int i = ty; i < 32; i += 8) {
        if (fok) {
            size_t o = ((size_t)b * D_ + d0 + i) * F_ + f0 + tx;
            out[o] = lat[o] - tile[tx][i];
        }
    }
}

__global__ void k_codes(const int* __restrict__ codes, float* __restrict__ out1) {
    int bi = blockIdx.x;
    int q = bi & 7, b = bi >> 3;
    for (int f = threadIdx.x; f < F_; f += 256)
        out1[(size_t)bi * F_ + f] = (float)codes[(size_t)q * N_ + (size_t)b * F_ + f];
}

__global__ void k_loss(const double* __restrict__ part, float* __restrict__ out2) {
    double s = 0.0;
    for (int i = threadIdx.x; i < Q_ * UPDBLK; i += 256) s += part[i];
#pragma unroll
    for (int off = 32; off; off >>= 1) s += __shfl_down(s, off, 64);
    __shared__ double red[4];
    int lane = threadIdx.x & 63, wv = threadIdx.x >> 6;
    if (lane == 0) red[wv] = s;
    __syncthreads();
    if (threadIdx.x == 0) {
        double tot = red[0] + red[1] + red[2] + red[3];
        float val = (float)(tot / ((double)Q_ * (double)B_ * (double)D_ * (double)F_));
        out2[0] = val;
        out2[1] = val;
    }
}

extern "C" void kernel_launch(void* const* d_in, const int* in_sizes, int n_in,
                              void* d_out, int out_size, void* d_ws, size_t ws_size,
                              hipStream_t stream) {
    const float* lat = (const float*)d_in[0];   // [16,512,1500] fp32
    const float* cb  = (const float*)d_in[1];   // [8,1024,512]  fp32
    char* ws = (char*)d_ws;
    float*    resT  = (float*)(ws);                          // 49,283,072
    short*    resbf = (short*)(ws + 49283072);               // 24,641,536
    short*    cbh   = (short*)(ws + 73924608);               //  8,388,608
    unsigned* candB = (unsigned*)(ws + 82313216);            //  6,144,000
    float*    Dmin  = (float*)(ws + 88457216);               //    770,048
    unsigned* cnt8  = (unsigned*)(ws + 89227264);            //    768,000
    unsigned* cand  = (unsigned*)(ws + 89995264);            //    768,000
    unsigned long long* rkey = (unsigned long long*)(ws + 90763264); // 192,000
    int*      codes = (int*)(ws + 90955264);                 //    768,000
    float*    Hq    = (float*)(ws + 91723264);               //     32,768
    float*    Sp    = (float*)(ws + 91756032);               //    384,000
    float*    Sn    = (float*)(ws + 92140032);               //     96,000
    double*   part  = (double*)(ws + 92236032);              //     24,064
    int*      gcount= (int*)(ws + 92260096);                 //         64
    float* out = (float*)d_out;

    hipLaunchKernelGGL(k_initT,    dim3(B_ * 16 * FB_), dim3(256), 0, stream, lat, resT, resbf);
    hipLaunchKernelGGL(k_cbh,      dim3(2048), dim3(256), 0, stream, cb, cbh);
    hipLaunchKernelGGL(k_cbnormP,  dim3(Q_ * C_ / 256), dim3(256), 0, stream, cb, Hq);
    hipLaunchKernelGGL(k_rownorm4, dim3(NBLK), dim3(256), 0, stream, resT, Sp);
    hipLaunchKernelGGL(k_ssum,     dim3(NBLK), dim3(256), 0, stream, Sp, Sn);

    for (int q = 0; q < Q_; ++q) {
        hipLaunchKernelGGL(k_gemm,    dim3(MPAD / 128, C_ / 128), dim3(256), 0, stream,
                           resbf, cbh, Hq, Dmin, candB, cnt8, gcount, q);
        hipLaunchKernelGGL(k_collect, dim3(N_ / 4), dim3(256), 0, stream,
                           Dmin, candB, cnt8, resT, cb, Hq, Sn, codes, cand, gcount, rkey, q);
        hipLaunchKernelGGL(k_rescore, dim3(CAP_ / 256), dim3(256), 0, stream,
                           cand, gcount, resT, cb, Hq, Sn, rkey, q);
        hipLaunchKernelGGL(k_upd,     dim3(UPDBLK), dim3(256), 0, stream,
                           resT, resbf, cb, codes, rkey, Sp, part, q);
        hipLaunchKernelGGL(k_ssum,    dim3(NBLK), dim3(256), 0, stream, Sp, Sn);
    }

    hipLaunchKernelGGL(k_out0T, dim3(B_ * 16 * FB_), dim3(256), 0, stream, lat, resT, out);
    hipLaunchKernelGGL(k_codes, dim3(B_ * Q_), dim3(256), 0, stream, codes, out + 12288000);
    hipLaunchKernelGGL(k_loss,  dim3(1), dim3(256), 0, stream, part, out + 12480000);
}

// Round 11
// 2805.010 us; speedup vs baseline: 8.3042x; 1.3095x over previous
//
#include <hip/hip_runtime.h>
#include <hip/hip_fp16.h>

// ResidualVectorQuantizer: B=16, D=512, F=1500, Q=8, C=1024
#define B_ 16
#define D_ 512
#define F_ 1500
#define N_ (B_*F_)   // 24000
#define Q_ 8
#define C_ 1024

constexpr int NBLK  = (N_ + 255) / 256;   // 94
constexpr int UPDBLK = 4 * NBLK;          // 376
constexpr int MPAD = 24064;               // padded rows (188*128)
constexpr int FB_  = (F_ + 31) / 32;      // 47

typedef __attribute__((ext_vector_type(8))) short bf16x8;
typedef __attribute__((ext_vector_type(4))) float f32x4;

__device__ __forceinline__ short f2bf(float f) {
    unsigned u = __float_as_uint(f);
    u += 0x7FFFu + ((u >> 16) & 1u);
    return (short)(u >> 16);
}
__device__ __forceinline__ float h2f(unsigned short u) {
    __half_raw r; r.x = u; return __half2float(__half(r));
}
__device__ __forceinline__ unsigned short f2h(float f) {
    __half h = __float2half(f);
    return __half_as_ushort(h);
}

// ---------------- init: resT/resbf[b*F+f][d] = lat[b][d][f] ----------------
__global__ void k_initT(const float* __restrict__ lat, float* __restrict__ resT,
                        short* __restrict__ resbf) {
    __shared__ float tile[32][33];
    int bi = blockIdx.x;
    int fb = bi % FB_, rem = bi / FB_;
    int db = rem & 15, b = rem >> 4;
    int tx = threadIdx.x & 31, ty = threadIdx.x >> 5;
    int f0 = fb * 32, d0 = db * 32;
    bool fok = (f0 + tx) < F_;
    for (int i = ty; i < 32; i += 8)
        if (fok) tile[i][tx] = lat[((size_t)b * D_ + d0 + i) * F_ + f0 + tx];
    __syncthreads();
    for (int i = ty; i < 32; i += 8) {
        int f = f0 + i;
        if (f < F_) {
            float v = tile[tx][i];
            size_t o = ((size_t)(b * F_ + f)) * D_ + d0 + tx;
            resT[o] = v;
            resbf[o] = f2bf(v);
        }
    }
}

// ---------------- cbh = bf16(cb) ----------------
__global__ void k_cbh(const float* __restrict__ cb, short* __restrict__ cbh) {
    size_t base = ((size_t)blockIdx.x * 256 + threadIdx.x) * 8;
    float4 a = *(const float4*)(cb + base);
    float4 b = *(const float4*)(cb + base + 4);
    bf16x8 o;
    o[0]=f2bf(a.x); o[1]=f2bf(a.y); o[2]=f2bf(a.z); o[3]=f2bf(a.w);
    o[4]=f2bf(b.x); o[5]=f2bf(b.y); o[6]=f2bf(b.z); o[7]=f2bf(b.w);
    *(bf16x8*)(cbh + base) = o;
}

// ---------------- H[q*C+c] = np.sum(cb*cb, axis=1), numpy pairwise fp32 (verified) ----------------
__global__ void k_cbnormP(const float* __restrict__ cb, float* __restrict__ Hq) {
#pragma clang fp contract(off)
    int wid = blockIdx.x * 256 + threadIdx.x;
    const float* p = cb + (size_t)wid * D_;
    float L[4];
#pragma unroll
    for (int l = 0; l < 4; ++l) {
        const float* pl = p + l * 128;
        float r[8];
#pragma unroll
        for (int j = 0; j < 8; ++j) { float x = pl[j]; r[j] = x * x; }
        for (int i = 8; i < 128; i += 8) {
#pragma unroll
            for (int j = 0; j < 8; ++j) { float x = pl[i + j]; r[j] = r[j] + x * x; }
        }
        L[l] = ((r[0] + r[1]) + (r[2] + r[3])) + ((r[4] + r[5]) + (r[6] + r[7]));
    }
    Hq[wid] = (L[0] + L[1]) + (L[2] + L[3]);
}

// ---------------- initial S partials (verified chain) ----------------
__global__ void k_rownorm4(const float* __restrict__ resT, float* __restrict__ Sp) {
#pragma clang fp contract(off)
    int n = blockIdx.x * 256 + threadIdx.x;
    if (n >= N_) return;
#pragma unroll
    for (int l = 0; l < 4; ++l) {
        const float* p = resT + (size_t)n * D_ + l * 128;
        float r[8];
#pragma unroll
        for (int j = 0; j < 8; ++j) { float x = p[j]; r[j] = x * x; }
        for (int i = 8; i < 128; i += 8) {
#pragma unroll
            for (int j = 0; j < 8; ++j) { float x = p[i + j]; r[j] = r[j] + x * x; }
        }
        Sp[(size_t)l * N_ + n] = ((r[0] + r[1]) + (r[2] + r[3])) + ((r[4] + r[5]) + (r[6] + r[7]));
    }
}

// ---------------- Sn[n] = pairwise top-join (verified) ----------------
__global__ void k_ssum(const float* __restrict__ Sp, float* __restrict__ Sn) {
#pragma clang fp contract(off)
    int n = blockIdx.x * 256 + threadIdx.x;
    if (n >= N_) return;
    Sn[n] = (Sp[n] + Sp[N_ + n]) + (Sp[2 * N_ + n] + Sp[3 * N_ + n]);
}

// ---------------- bf16 MFMA screen GEMM: per-row-block candidate slots ----------------
#define LSTR 80
__global__ __launch_bounds__(256) void k_gemm(
        const short* __restrict__ resbf, const short* __restrict__ cbh,
        const float* __restrict__ Hq, float* __restrict__ Dmin,
        unsigned* __restrict__ candBuf, unsigned* __restrict__ cnt8, int q) {
    __shared__ short xh[128 * LSTR];
    __shared__ short ch[128 * LSTR];
    __shared__ float smin[128][2];
    __shared__ float bminL[128];
    __shared__ unsigned lcnt[128];
    __shared__ unsigned slots[128][8];

    const int t = threadIdx.x;
    const int n0 = blockIdx.x * 128;
    const int cby = blockIdx.y;
    const int c0 = cby * 128;
    const int l = t & 63, w = t >> 6;
    const int wr = w >> 1, wc = w & 1;
    const short* cbhq = cbh + ((size_t)q * C_) * D_;

    f32x4 acc[4][4];
#pragma unroll
    for (int i = 0; i < 4; ++i)
#pragma unroll
        for (int j = 0; j < 4; ++j) { acc[i][j][0]=0.f; acc[i][j][1]=0.f; acc[i][j][2]=0.f; acc[i][j][3]=0.f; }

    for (int kc = 0; kc < D_; kc += 64) {
        __syncthreads();
#pragma unroll
        for (int p = 0; p < 4; ++p) {
            int idx = p * 256 + t;
            int nn = idx >> 3, d8 = idx & 7;
            *(bf16x8*)(&xh[nn * LSTR + d8 * 8]) =
                *(const bf16x8*)(resbf + (size_t)(n0 + nn) * D_ + kc + d8 * 8);
        }
#pragma unroll
        for (int p = 0; p < 4; ++p) {
            int idx = p * 256 + t;
            int cr = idx >> 3, d8 = idx & 7;
            *(bf16x8*)(&ch[cr * LSTR + d8 * 8]) =
                *(const bf16x8*)(cbhq + (size_t)(c0 + cr) * D_ + kc + d8 * 8);
        }
        __syncthreads();

#pragma unroll
        for (int kf = 0; kf < 2; ++kf) {
            const int ko = kf * 32 + (l >> 4) * 8;
            bf16x8 ah[4], bh[4];
#pragma unroll
            for (int i = 0; i < 4; ++i) {
                ah[i] = *(const bf16x8*)(&xh[(wr * 64 + i * 16 + (l & 15)) * LSTR + ko]);
                bh[i] = *(const bf16x8*)(&ch[(wc * 64 + i * 16 + (l & 15)) * LSTR + ko]);
            }
#pragma unroll
            for (int i = 0; i < 4; ++i)
#pragma unroll
                for (int j = 0; j < 4; ++j)
                    acc[i][j] = __builtin_amdgcn_mfma_f32_16x16x32_bf16(ah[i], bh[j], acc[i][j], 0, 0, 0);
        }
    }

    const float* Hqq = Hq + (size_t)q * C_;
    float hv[4];
#pragma unroll
    for (int j = 0; j < 4; ++j) hv[j] = Hqq[c0 + wc * 64 + j * 16 + (l & 15)];

    // pass 1: row minima of (H - 2A)
#pragma unroll
    for (int i = 0; i < 4; ++i)
#pragma unroll
        for (int r = 0; r < 4; ++r) {
            float vm = hv[0] - 2.0f * acc[i][0][r];
#pragma unroll
            for (int j = 1; j < 4; ++j) vm = fminf(vm, hv[j] - 2.0f * acc[i][j][r]);
            vm = fminf(vm, __shfl_xor(vm, 1, 64));
            vm = fminf(vm, __shfl_xor(vm, 2, 64));
            vm = fminf(vm, __shfl_xor(vm, 4, 64));
            vm = fminf(vm, __shfl_xor(vm, 8, 64));
            if ((l & 15) == 0) smin[wr * 64 + i * 16 + (l >> 4) * 4 + r][wc] = vm;
        }
    __syncthreads();
    if (t < 128) {
        bminL[t] = fminf(smin[t][0], smin[t][1]);
        lcnt[t] = 0;
    }
    __syncthreads();
    // pass 2: emit slots within blockmin + 4e-3
#pragma unroll
    for (int i = 0; i < 4; ++i)
#pragma unroll
        for (int j = 0; j < 4; ++j)
#pragma unroll
            for (int r = 0; r < 4; ++r) {
                int row = wr * 64 + i * 16 + (l >> 4) * 4 + r;
                float v = hv[j] - 2.0f * acc[i][j][r];
                if (v <= bminL[row] + 4e-3f) {
                    unsigned pos = atomicAdd(&lcnt[row], 1u);
                    if (pos < 8) {
                        unsigned c = (unsigned)(c0 + wc * 64 + j * 16 + (l & 15));
                        slots[row][pos] = ((unsigned)f2h(v) << 16) | c;
                    }
                }
            }
    __syncthreads();
    if (t < 128 && (n0 + t) < N_) {
        int n = n0 + t;
        Dmin[(size_t)n * 8 + cby] = bminL[t];
        unsigned cnt = lcnt[t];
        cnt8[(size_t)n * 8 + cby] = cnt;
        unsigned m = cnt < 8u ? cnt : 8u;
        for (unsigned s = 0; s < m; ++s)
            candBuf[((size_t)n * 8 + cby) * 8 + s] = slots[t][s];
    }
}

// ---------------- collect: ballot-prefix into fixed 8 slots, no global atomics ----------------
__global__ __launch_bounds__(256) void k_collect(
        const float* __restrict__ Dmin, const unsigned* __restrict__ candBuf,
        const unsigned* __restrict__ cnt8, const float* __restrict__ resT,
        const float* __restrict__ cb, const float* __restrict__ Hq,
        const float* __restrict__ Sn, int* __restrict__ codes,
        unsigned* __restrict__ cand, unsigned* __restrict__ rcnt,
        unsigned long long* __restrict__ rkey, int q) {
#pragma clang fp contract(off)
    const int w = threadIdx.x >> 6, lane = threadIdx.x & 63;
    const int n = blockIdx.x * 4 + w;

    float dml = 3.4e38f;
    unsigned cl = 0u;
    if (lane < 8) {
        dml = Dmin[(size_t)n * 8 + lane];
        cl  = cnt8[(size_t)n * 8 + lane];
    }
    float m = dml;
    m = fminf(m, __shfl_xor(m, 4, 64));
    m = fminf(m, __shfl_xor(m, 2, 64));
    m = fminf(m, __shfl_xor(m, 1, 64));
    m = __shfl(m, 0, 64);
    const float thr = m + 4e-3f + 1e-4f;

    // fallback only if a truncated block could actually hold a sub-thr candidate
    bool ovf = __any(lane < 8 && cl > 8u && dml <= thr);

    if (!ovf) {
        int blk = lane >> 3, s = lane & 7;
        unsigned cb8 = __shfl(cl, blk, 64);
        if (cb8 > 8u) cb8 = 8u;
        bool has = false; unsigned myc = 0;
        if ((unsigned)s < cb8) {
            unsigned e = candBuf[((size_t)n * 8 + blk) * 8 + s];
            float vh = h2f((unsigned short)(e >> 16));
            if (vh <= thr) { has = true; myc = e & 0x3FFu; }
        }
        unsigned long long mask = __ballot(has);
        int tot = __popcll(mask);
        if (tot == 1) {
            if (has) codes[(size_t)q * N_ + n] = (int)myc;
            if (lane == 0) rcnt[n] = 0u;
            return;
        }
        if (tot <= 8) {
            int pre = __popcll(mask & ((1ull << lane) - 1ull));
            if (has) cand[(size_t)n * 8 + pre] = myc;
            if (lane == 0) {
                rcnt[n] = (unsigned)tot;
                rkey[n] = ~0ull;
                codes[(size_t)q * N_ + n] = -1;
            }
            return;
        }
        ovf = true;
    }
    // exact full-row fallback (rare): wave-parallel, verified chain per c
    {
        const float S = Sn[n];
        const float* xr = resT + (size_t)n * D_;
        const float* cbq = cb + (size_t)q * ((size_t)C_ * D_);
        const float* Hqq = Hq + (size_t)q * C_;
        float bv = 3.4e38f; int bc = 0x7fffffff;
        for (int rep = 0; rep < 16; ++rep) {
            int c = lane + rep * 64;
            const float* cr = cbq + (size_t)c * D_;
            float A = 0.0f;
            for (int d = 0; d < D_; ++d) A = fmaf(xr[d], cr[d], A);
            float v = (S - 2.0f * A) + Hqq[c];
            if (v < bv || (v == bv && c < bc)) { bv = v; bc = c; }
        }
        for (int off = 32; off; off >>= 1) {
            float ov = __shfl_xor(bv, off, 64);
            int oc = __shfl_xor(bc, off, 64);
            if (ov < bv || (ov == bv && oc < bc)) { bv = ov; bc = oc; }
        }
        if (lane == 0) { codes[(size_t)q * N_ + n] = bc; rcnt[n] = 0u; }
    }
}

// ---------------- rescore: thread=(row,slot), exact chain, per-row atomicMin ----------------
__global__ __launch_bounds__(256) void k_rescore(
        const unsigned* __restrict__ cand, const unsigned* __restrict__ rcnt,
        const float* __restrict__ resT, const float* __restrict__ cb,
        const float* __restrict__ Hq, const float* __restrict__ Sn,
        unsigned long long* __restrict__ rkey, int q) {
#pragma clang fp contract(off)
    int tid = blockIdx.x * 256 + threadIdx.x;   // grid covers N_*8
    int n = tid >> 3, s = tid & 7;
    if ((unsigned)s >= rcnt[n]) return;
    int c = (int)cand[(size_t)n * 8 + s];
    const float* xr = resT + (size_t)n * D_;
    const float* cr = cb + ((size_t)q * C_ + c) * D_;
    float A = 0.0f;
#pragma unroll 8
    for (int d = 0; d < D_; ++d) A = fmaf(xr[d], cr[d], A);
    float v = (Sn[n] - 2.0f * A) + Hq[(size_t)q * C_ + c];
    unsigned long long key = ((unsigned long long)__float_as_uint(v) << 32) | (unsigned)c;
    atomicMin(&rkey[n], key);
}

// ---------------- fused residual update + bf16 shadow + S partials + loss (verified) ----------------
__global__ __launch_bounds__(256) void k_upd(
        float* __restrict__ resT, short* __restrict__ resbf,
        const float* __restrict__ cb, int* __restrict__ codes,
        const unsigned long long* __restrict__ rkey,
        float* __restrict__ Sp, double* __restrict__ part, int q) {
#pragma clang fp contract(off)
    int seg = blockIdx.x / NBLK;
    int nb  = blockIdx.x % NBLK;
    int n = nb * 256 + threadIdx.x;
    float L = 0.0f;
    if (n < N_) {
        int idx = codes[(size_t)q * N_ + n];
        if (idx < 0) idx = (int)(rkey[n] & 0x3FFull);
        if (seg == 0) codes[(size_t)q * N_ + n] = idx;   // benign same-value race
        const float* crow = cb + ((size_t)q * C_ + idx) * D_ + seg * 128;
        float* rp = resT + (size_t)n * D_ + seg * 128;
        short* rb = resbf + (size_t)n * D_ + seg * 128;
        float r8[8];
#pragma unroll
        for (int j = 0; j < 8; ++j) {
            float r = rp[j] - crow[j];
            rp[j] = r; rb[j] = f2bf(r);
            r8[j] = r * r;
        }
        for (int i = 8; i < 128; i += 8) {
#pragma unroll
            for (int j = 0; j < 8; ++j) {
                float r = rp[i + j] - crow[i + j];
                rp[i + j] = r; rb[i + j] = f2bf(r);
                r8[j] = r8[j] + r * r;
            }
        }
        L = ((r8[0] + r8[1]) + (r8[2] + r8[3])) + ((r8[4] + r8[5]) + (r8[6] + r8[7]));
        Sp[(size_t)seg * N_ + n] = L;
    }
    double s = (double)L;
#pragma unroll
    for (int off = 32; off; off >>= 1) s += __shfl_down(s, off, 64);
    __shared__ double sred[4];
    int lane = threadIdx.x & 63, wv = threadIdx.x >> 6;
    if (lane == 0) sred[wv] = s;
    __syncthreads();
    if (threadIdx.x == 0)
        part[(size_t)q * UPDBLK + blockIdx.x] = sred[0] + sred[1] + sred[2] + sred[3];
}

// ---------------- outputs ----------------
__global__ void k_out0T(const float* __restrict__ lat, const float* __restrict__ resT,
                        float* __restrict__ out) {
    __shared__ float tile[32][33];
    int bi = blockIdx.x;
    int fb = bi % FB_, rem = bi / FB_;
    int db = rem & 15, b = rem >> 4;
    int tx = threadIdx.x & 31, ty = threadIdx.x >> 5;
    int f0 = fb * 32, d0 = db * 32;
    for (int i = ty; i < 32; i += 8) {
        int f = f0 + i;
        if (f < F_) tile[i][tx] = resT[((size_t)(b * F_ + f)) * D_ + d0 + tx];
    }
    __syncthreads();
    bool fok = (f0 + tx) < F_;
    for (int i = ty; i < 32; i += 8) {
        if (fok) {
            size_t o = ((size_t)b * D_ + d0 + i) * F_ + f0 + tx;
            out[o] = lat[o] - tile[tx][i];
        }
    }
}

__global__ void k_codes(const int* __restrict__ codes, float* __restrict__ out1) {
    int bi = blockIdx.x;
    int q = bi & 7, b = bi >> 3;
    for (int f = threadIdx.x; f < F_; f += 256)
        out1[(size_t)bi * F_ + f] = (float)codes[(size_t)q * N_ + (size_t)b * F_ + f];
}

__global__ void k_loss(const double* __restrict__ part, float* __restrict__ out2) {
    double s = 0.0;
    for (int i = threadIdx.x; i < Q_ * UPDBLK; i += 256) s += part[i];
#pragma unroll
    for (int off = 32; off; off >>= 1) s += __shfl_down(s, off, 64);
    __shared__ double red[4];
    int lane = threadIdx.x & 63, wv = threadIdx.x >> 6;
    if (lane == 0) red[wv] = s;
    __syncthreads();
    if (threadIdx.x == 0) {
        double tot = red[0] + red[1] + red[2] + red[3];
        float val = (float)(tot / ((double)Q_ * (double)B_ * (double)D_ * (double)F_));
        out2[0] = val;
        out2[1] = val;
    }
}

extern "C" void kernel_launch(void* const* d_in, const int* in_sizes, int n_in,
                              void* d_out, int out_size, void* d_ws, size_t ws_size,
                              hipStream_t stream) {
    const float* lat = (const float*)d_in[0];   // [16,512,1500] fp32
    const float* cb  = (const float*)d_in[1];   // [8,1024,512]  fp32
    char* ws = (char*)d_ws;
    float*    resT  = (float*)(ws);                          // 49,283,072
    short*    resbf = (short*)(ws + 49283072);               // 24,641,536
    short*    cbh   = (short*)(ws + 73924608);               //  8,388,608
    unsigned* candB = (unsigned*)(ws + 82313216);            //  6,144,000
    float*    Dmin  = (float*)(ws + 88457216);               //    768,000
    unsigned* cnt8  = (unsigned*)(ws + 89227264);            //    768,000
    unsigned* cand  = (unsigned*)(ws + 89995264);            //    768,000
    unsigned* rcnt  = (unsigned*)(ws + 90763264);            //     96,000
    unsigned long long* rkey = (unsigned long long*)(ws + 90859264); // 192,000
    int*      codes = (int*)(ws + 91051264);                 //    768,000
    float*    Hq    = (float*)(ws + 91819264);               //     32,768
    float*    Sp    = (float*)(ws + 91852032);               //    384,000
    float*    Sn    = (float*)(ws + 92236032);               //     96,000
    double*   part  = (double*)(ws + 92332032);              //     24,064
    float* out = (float*)d_out;

    hipLaunchKernelGGL(k_initT,    dim3(B_ * 16 * FB_), dim3(256), 0, stream, lat, resT, resbf);
    hipLaunchKernelGGL(k_cbh,      dim3(2048), dim3(256), 0, stream, cb, cbh);
    hipLaunchKernelGGL(k_cbnormP,  dim3(Q_ * C_ / 256), dim3(256), 0, stream, cb, Hq);
    hipLaunchKernelGGL(k_rownorm4, dim3(NBLK), dim3(256), 0, stream, resT, Sp);
    hipLaunchKernelGGL(k_ssum,     dim3(NBLK), dim3(256), 0, stream, Sp, Sn);

    for (int q = 0; q < Q_; ++q) {
        hipLaunchKernelGGL(k_gemm,    dim3(MPAD / 128, C_ / 128), dim3(256), 0, stream,
                           resbf, cbh, Hq, Dmin, candB, cnt8, q);
        hipLaunchKernelGGL(k_collect, dim3(N_ / 4), dim3(256), 0, stream,
                           Dmin, candB, cnt8, resT, cb, Hq, Sn, codes, cand, rcnt, rkey, q);
        hipLaunchKernelGGL(k_rescore, dim3(N_ * 8 / 256), dim3(256), 0, stream,
                           cand, rcnt, resT, cb, Hq, Sn, rkey, q);
        hipLaunchKernelGGL(k_upd,     dim3(UPDBLK), dim3(256), 0, stream,
                           resT, resbf, cb, codes, rkey, Sp, part, q);
        hipLaunchKernelGGL(k_ssum,    dim3(NBLK), dim3(256), 0, stream, Sp, Sn);
    }

    hipLaunchKernelGGL(k_out0T, dim3(B_ * 16 * FB_), dim3(256), 0, stream, lat, resT, out);
    hipLaunchKernelGGL(k_codes, dim3(B_ * Q_), dim3(256), 0, stream, codes, out + 12288000);
    hipLaunchKernelGGL(k_loss,  dim3(1), dim3(256), 0, stream, part, out + 12480000);
}

// Round 12
// 2108.180 us; speedup vs baseline: 11.0491x; 1.3305x over previous
//
#include <hip/hip_runtime.h>
#include <hip/hip_fp16.h>

// ResidualVectorQuantizer: B=16, D=512, F=1500, Q=8, C=1024
#define B_ 16
#define D_ 512
#define F_ 1500
#define N_ (B_*F_)   // 24000
#define Q_ 8
#define C_ 1024

constexpr int NBLK  = (N_ + 255) / 256;   // 94
constexpr int UPDBLK = 4 * NBLK;          // 376
constexpr int MPAD = 24064;               // padded rows (188*128)
constexpr int FB_  = (F_ + 31) / 32;      // 47
constexpr int TILES_ = B_ * 16 * FB_;     // 12032 transpose tiles

typedef __attribute__((ext_vector_type(8))) short bf16x8;
typedef __attribute__((ext_vector_type(4))) float f32x4;

__device__ __forceinline__ short f2bf(float f) {
    unsigned u = __float_as_uint(f);
    u += 0x7FFFu + ((u >> 16) & 1u);
    return (short)(u >> 16);
}
__device__ __forceinline__ float h2f(unsigned short u) {
    __half_raw r; r.x = u; return __half2float(__half(r));
}
__device__ __forceinline__ unsigned short f2h(float f) {
    __half h = __float2half(f);
    return __half_as_ushort(h);
}

// ---------------- init: resT/resbf[b*F+f][d] = lat[b][d][f] (grid-stride tiles) ----------------
__global__ __launch_bounds__(256) void k_initT(const float* __restrict__ lat,
                                               float* __restrict__ resT,
                                               short* __restrict__ resbf) {
    __shared__ float tile[32][33];
    int tx = threadIdx.x & 31, ty = threadIdx.x >> 5;
    for (int bi = blockIdx.x; bi < TILES_; bi += 512) {
        int fb = bi % FB_, rem = bi / FB_;
        int db = rem & 15, b = rem >> 4;
        int f0 = fb * 32, d0 = db * 32;
        bool fok = (f0 + tx) < F_;
        for (int i = ty; i < 32; i += 8)
            if (fok) tile[i][tx] = lat[((size_t)b * D_ + d0 + i) * F_ + f0 + tx];
        __syncthreads();
        for (int i = ty; i < 32; i += 8) {
            int f = f0 + i;
            if (f < F_) {
                float v = tile[tx][i];
                size_t o = ((size_t)(b * F_ + f)) * D_ + d0 + tx;
                resT[o] = v;
                resbf[o] = f2bf(v);
            }
        }
        __syncthreads();
    }
}

// ---------------- cbh = bf16(cb) (grid-stride) ----------------
__global__ void k_cbh(const float* __restrict__ cb, short* __restrict__ cbh) {
    for (int g = blockIdx.x * 256 + threadIdx.x; g < Q_ * C_ * D_ / 8; g += 512 * 256) {
        size_t base = (size_t)g * 8;
        float4 a = *(const float4*)(cb + base);
        float4 b = *(const float4*)(cb + base + 4);
        bf16x8 o;
        o[0]=f2bf(a.x); o[1]=f2bf(a.y); o[2]=f2bf(a.z); o[3]=f2bf(a.w);
        o[4]=f2bf(b.x); o[5]=f2bf(b.y); o[6]=f2bf(b.z); o[7]=f2bf(b.w);
        *(bf16x8*)(cbh + base) = o;
    }
}

// ---------------- H[q*C+c] = np.sum(cb*cb, axis=1), numpy pairwise fp32 (verified) ----------------
__global__ void k_cbnormP(const float* __restrict__ cb, float* __restrict__ Hq) {
#pragma clang fp contract(off)
    int wid = blockIdx.x * 256 + threadIdx.x;
    const float* p = cb + (size_t)wid * D_;
    float L[4];
#pragma unroll
    for (int l = 0; l < 4; ++l) {
        const float* pl = p + l * 128;
        float r[8];
#pragma unroll
        for (int j = 0; j < 8; ++j) { float x = pl[j]; r[j] = x * x; }
        for (int i = 8; i < 128; i += 8) {
#pragma unroll
            for (int j = 0; j < 8; ++j) { float x = pl[i + j]; r[j] = r[j] + x * x; }
        }
        L[l] = ((r[0] + r[1]) + (r[2] + r[3])) + ((r[4] + r[5]) + (r[6] + r[7]));
    }
    Hq[wid] = (L[0] + L[1]) + (L[2] + L[3]);
}

// ---------------- initial S partials (verified chain) ----------------
__global__ void k_rownorm4(const float* __restrict__ resT, float* __restrict__ Sp) {
#pragma clang fp contract(off)
    int n = blockIdx.x * 256 + threadIdx.x;
    if (n >= N_) return;
#pragma unroll
    for (int l = 0; l < 4; ++l) {
        const float* p = resT + (size_t)n * D_ + l * 128;
        float r[8];
#pragma unroll
        for (int j = 0; j < 8; ++j) { float x = p[j]; r[j] = x * x; }
        for (int i = 8; i < 128; i += 8) {
#pragma unroll
            for (int j = 0; j < 8; ++j) { float x = p[i + j]; r[j] = r[j] + x * x; }
        }
        Sp[(size_t)l * N_ + n] = ((r[0] + r[1]) + (r[2] + r[3])) + ((r[4] + r[5]) + (r[6] + r[7]));
    }
}

// ---------------- bf16 MFMA screen GEMM: per-row-block candidate slots (2 n-tiles/block) ----------------
#define LSTR 80
__global__ __launch_bounds__(256) void k_gemm(
        const short* __restrict__ resbf, const short* __restrict__ cbh,
        const float* __restrict__ Hq, float* __restrict__ Dmin,
        unsigned* __restrict__ candBuf, unsigned* __restrict__ cnt8, int q) {
    __shared__ short xh[128 * LSTR];
    __shared__ short ch[128 * LSTR];
    __shared__ float smin[128][2];
    __shared__ float bminL[128];
    __shared__ unsigned lcnt[128];
    __shared__ unsigned slots[128][8];

    const int t = threadIdx.x;
    const int cby = blockIdx.y;
    const int c0 = cby * 128;
    const int l = t & 63, w = t >> 6;
    const int wr = w >> 1, wc = w & 1;
    const short* cbhq = cbh + ((size_t)q * C_) * D_;
    const float* Hqq = Hq + (size_t)q * C_;

    for (int nt = 0; nt < 2; ++nt) {
        const int n0 = (blockIdx.x * 2 + nt) * 128;

        f32x4 acc[4][4];
#pragma unroll
        for (int i = 0; i < 4; ++i)
#pragma unroll
            for (int j = 0; j < 4; ++j) { acc[i][j][0]=0.f; acc[i][j][1]=0.f; acc[i][j][2]=0.f; acc[i][j][3]=0.f; }

        for (int kc = 0; kc < D_; kc += 64) {
            __syncthreads();
#pragma unroll
            for (int p = 0; p < 4; ++p) {
                int idx = p * 256 + t;
                int nn = idx >> 3, d8 = idx & 7;
                *(bf16x8*)(&xh[nn * LSTR + d8 * 8]) =
                    *(const bf16x8*)(resbf + (size_t)(n0 + nn) * D_ + kc + d8 * 8);
            }
#pragma unroll
            for (int p = 0; p < 4; ++p) {
                int idx = p * 256 + t;
                int cr = idx >> 3, d8 = idx & 7;
                *(bf16x8*)(&ch[cr * LSTR + d8 * 8]) =
                    *(const bf16x8*)(cbhq + (size_t)(c0 + cr) * D_ + kc + d8 * 8);
            }
            __syncthreads();

#pragma unroll
            for (int kf = 0; kf < 2; ++kf) {
                const int ko = kf * 32 + (l >> 4) * 8;
                bf16x8 ah[4], bh[4];
#pragma unroll
                for (int i = 0; i < 4; ++i) {
                    ah[i] = *(const bf16x8*)(&xh[(wr * 64 + i * 16 + (l & 15)) * LSTR + ko]);
                    bh[i] = *(const bf16x8*)(&ch[(wc * 64 + i * 16 + (l & 15)) * LSTR + ko]);
                }
#pragma unroll
                for (int i = 0; i < 4; ++i)
#pragma unroll
                    for (int j = 0; j < 4; ++j)
                        acc[i][j] = __builtin_amdgcn_mfma_f32_16x16x32_bf16(ah[i], bh[j], acc[i][j], 0, 0, 0);
            }
        }

        float hv[4];
#pragma unroll
        for (int j = 0; j < 4; ++j) hv[j] = Hqq[c0 + wc * 64 + j * 16 + (l & 15)];

        // pass 1: row minima of (H - 2A)
#pragma unroll
        for (int i = 0; i < 4; ++i)
#pragma unroll
            for (int r = 0; r < 4; ++r) {
                float vm = hv[0] - 2.0f * acc[i][0][r];
#pragma unroll
                for (int j = 1; j < 4; ++j) vm = fminf(vm, hv[j] - 2.0f * acc[i][j][r]);
                vm = fminf(vm, __shfl_xor(vm, 1, 64));
                vm = fminf(vm, __shfl_xor(vm, 2, 64));
                vm = fminf(vm, __shfl_xor(vm, 4, 64));
                vm = fminf(vm, __shfl_xor(vm, 8, 64));
                if ((l & 15) == 0) smin[wr * 64 + i * 16 + (l >> 4) * 4 + r][wc] = vm;
            }
        __syncthreads();
        if (t < 128) {
            bminL[t] = fminf(smin[t][0], smin[t][1]);
            lcnt[t] = 0;
        }
        __syncthreads();
        // pass 2: emit slots within blockmin + 1.6e-3
#pragma unroll
        for (int i = 0; i < 4; ++i)
#pragma unroll
            for (int j = 0; j < 4; ++j)
#pragma unroll
                for (int r = 0; r < 4; ++r) {
                    int row = wr * 64 + i * 16 + (l >> 4) * 4 + r;
                    float v = hv[j] - 2.0f * acc[i][j][r];
                    if (v <= bminL[row] + 1.6e-3f) {
                        unsigned pos = atomicAdd(&lcnt[row], 1u);
                        if (pos < 8) {
                            unsigned c = (unsigned)(c0 + wc * 64 + j * 16 + (l & 15));
                            slots[row][pos] = ((unsigned)f2h(v) << 16) | c;
                        }
                    }
                }
        __syncthreads();
        if (t < 128 && (n0 + t) < N_) {
            int n = n0 + t;
            Dmin[(size_t)n * 8 + cby] = bminL[t];
            unsigned cnt = lcnt[t];
            cnt8[(size_t)n * 8 + cby] = cnt;
            unsigned mm = cnt < 8u ? cnt : 8u;
            for (unsigned s = 0; s < mm; ++s)
                candBuf[((size_t)n * 8 + cby) * 8 + s] = slots[t][s];
        }
        __syncthreads();
    }
}

// ---------------- fused collect + exact rescore (512 blocks, wave-per-row grid-stride) ----------------
__global__ __launch_bounds__(256) void k_collect2(
        const float* __restrict__ Dmin, const unsigned* __restrict__ candBuf,
        const unsigned* __restrict__ cnt8, const float* __restrict__ resT,
        const float* __restrict__ cb, const float* __restrict__ Hq,
        const float* __restrict__ Sp, int* __restrict__ codes, int q) {
#pragma clang fp contract(off)
    const int w = threadIdx.x >> 6, lane = threadIdx.x & 63;
    const float* cbq = cb + (size_t)q * ((size_t)C_ * D_);
    const float* Hqq = Hq + (size_t)q * C_;

    for (int n = blockIdx.x * 4 + w; n < N_; n += 2048) {
        float dml = 3.4e38f; unsigned cl = 0u;
        if (lane < 8) { dml = Dmin[(size_t)n * 8 + lane]; cl = cnt8[(size_t)n * 8 + lane]; }
        float m = dml;
        m = fminf(m, __shfl_xor(m, 4, 64));
        m = fminf(m, __shfl_xor(m, 2, 64));
        m = fminf(m, __shfl_xor(m, 1, 64));
        m = __shfl(m, 0, 64);
        const float thr = m + 1.5e-3f;

        int code = -1;
        bool ovf = __any(lane < 8 && cl > 8u && dml <= thr + 1e-4f);
        if (!ovf) {
            int blk = lane >> 3, s = lane & 7;
            unsigned cb8 = __shfl(cl, blk, 64);
            if (cb8 > 8u) cb8 = 8u;
            bool has = false; int myc = 0x7fffffff;
            if ((unsigned)s < cb8) {
                unsigned e = candBuf[((size_t)n * 8 + blk) * 8 + s];
                if (h2f((unsigned short)(e >> 16)) <= thr) { has = true; myc = (int)(e & 0x3FFu); }
            }
            unsigned long long mask = __ballot(has);
            int tot = __popcll(mask);
            if (tot == 1) {
                int src = __ffsll((unsigned long long)mask) - 1;
                code = __shfl(myc, src, 64);
            } else if (tot >= 2 && tot <= 8) {
                float S = (Sp[n] + Sp[N_ + n]) + (Sp[2 * N_ + n] + Sp[3 * N_ + n]);
                float bv = 3.4e38f; int bc = 0x7fffffff;
                if (has) {
                    const float* xr = resT + (size_t)n * D_;
                    const float* cr = cbq + (size_t)myc * D_;
                    float A = 0.0f;
#pragma unroll 8
                    for (int d = 0; d < D_; ++d) A = fmaf(xr[d], cr[d], A);  // verified exact chain
                    bv = (S - 2.0f * A) + Hqq[myc];
                    bc = myc;
                }
                for (int off = 32; off; off >>= 1) {
                    float ov = __shfl_xor(bv, off, 64);
                    int oc = __shfl_xor(bc, off, 64);
                    if (ov < bv || (ov == bv && oc < bc)) { bv = ov; bc = oc; }
                }
                code = bc;
            } else {
                ovf = true;   // tot > 8 (tot==0 impossible)
            }
        }
        if (ovf) {
            // rare fallback: approximate full row (any-order fp32), exact-chain the shortlist
            float S = (Sp[n] + Sp[N_ + n]) + (Sp[2 * N_ + n] + Sp[3 * N_ + n]);
            const float4* xr4 = (const float4*)(resT + (size_t)n * D_);
            float mn = 3.4e38f;
            for (int rep = 0; rep < 16; ++rep) {
                int c = lane + rep * 64;
                const float4* cr4 = (const float4*)(cbq + (size_t)c * D_);
                float a0 = 0.f, a1 = 0.f, a2 = 0.f, a3 = 0.f;
#pragma unroll 4
                for (int d4 = 0; d4 < 128; ++d4) {
                    float4 xv = xr4[d4], cv = cr4[d4];
                    a0 = fmaf(xv.x, cv.x, a0); a1 = fmaf(xv.y, cv.y, a1);
                    a2 = fmaf(xv.z, cv.z, a2); a3 = fmaf(xv.w, cv.w, a3);
                }
                float v = (S - 2.0f * ((a0 + a1) + (a2 + a3))) + Hqq[c];
                mn = fminf(mn, v);
            }
            for (int off = 32; off; off >>= 1) mn = fminf(mn, __shfl_xor(mn, off, 64));
            const float thr2 = mn + 6e-4f;
            float bv = 3.4e38f; int bc = 0x7fffffff;
            const float* xr = resT + (size_t)n * D_;
            for (int rep = 0; rep < 16; ++rep) {
                int c = lane + rep * 64;
                const float4* cr4 = (const float4*)(cbq + (size_t)c * D_);
                float a0 = 0.f, a1 = 0.f, a2 = 0.f, a3 = 0.f;
#pragma unroll 4
                for (int d4 = 0; d4 < 128; ++d4) {
                    float4 xv = xr4[d4], cv = cr4[d4];
                    a0 = fmaf(xv.x, cv.x, a0); a1 = fmaf(xv.y, cv.y, a1);
                    a2 = fmaf(xv.z, cv.z, a2); a3 = fmaf(xv.w, cv.w, a3);
                }
                float vap = (S - 2.0f * ((a0 + a1) + (a2 + a3))) + Hqq[c];
                if (vap <= thr2) {
                    const float* cr = cbq + (size_t)c * D_;
                    float A = 0.0f;
#pragma unroll 8
                    for (int d = 0; d < D_; ++d) A = fmaf(xr[d], cr[d], A);
                    float v = (S - 2.0f * A) + Hqq[c];
                    if (v < bv || (v == bv && c < bc)) { bv = v; bc = c; }
                }
            }
            for (int off = 32; off; off >>= 1) {
                float ov = __shfl_xor(bv, off, 64);
                int oc = __shfl_xor(bc, off, 64);
                if (ov < bv || (ov == bv && oc < bc)) { bv = ov; bc = oc; }
            }
            code = bc;
        }
        if (lane == 0) codes[(size_t)q * N_ + n] = code;
    }
}

// ---------------- fused residual update + bf16 shadow + S partials + loss (verified) ----------------
__global__ __launch_bounds__(256) void k_upd(
        float* __restrict__ resT, short* __restrict__ resbf,
        const float* __restrict__ cb, const int* __restrict__ codes,
        float* __restrict__ Sp, double* __restrict__ part, int q) {
#pragma clang fp contract(off)
    int seg = blockIdx.x / NBLK;
    int nb  = blockIdx.x % NBLK;
    int n = nb * 256 + threadIdx.x;
    float L = 0.0f;
    if (n < N_) {
        int idx = codes[(size_t)q * N_ + n];
        const float* crow = cb + ((size_t)q * C_ + idx) * D_ + seg * 128;
        float* rp = resT + (size_t)n * D_ + seg * 128;
        short* rb = resbf + (size_t)n * D_ + seg * 128;
        float r8[8];
#pragma unroll
        for (int j = 0; j < 8; ++j) {
            float r = rp[j] - crow[j];
            rp[j] = r; rb[j] = f2bf(r);
            r8[j] = r * r;
        }
        for (int i = 8; i < 128; i += 8) {
#pragma unroll
            for (int j = 0; j < 8; ++j) {
                float r = rp[i + j] - crow[i + j];
                rp[i + j] = r; rb[i + j] = f2bf(r);
                r8[j] = r8[j] + r * r;
            }
        }
        L = ((r8[0] + r8[1]) + (r8[2] + r8[3])) + ((r8[4] + r8[5]) + (r8[6] + r8[7]));
        Sp[(size_t)seg * N_ + n] = L;
    }
    double s = (double)L;
#pragma unroll
    for (int off = 32; off; off >>= 1) s += __shfl_down(s, off, 64);
    __shared__ double sred[4];
    int lane = threadIdx.x & 63, wv = threadIdx.x >> 6;
    if (lane == 0) sred[wv] = s;
    __syncthreads();
    if (threadIdx.x == 0)
        part[(size_t)q * UPDBLK + blockIdx.x] = sred[0] + sred[1] + sred[2] + sred[3];
}

// ---------------- outputs ----------------
__global__ __launch_bounds__(256) void k_out0T(const float* __restrict__ lat,
                                               const float* __restrict__ resT,
                                               float* __restrict__ out) {
    __shared__ float tile[32][33];
    int tx = threadIdx.x & 31, ty = threadIdx.x >> 5;
    for (int bi = blockIdx.x; bi < TILES_; bi += 512) {
        int fb = bi % FB_, rem = bi / FB_;
        int db = rem & 15, b = rem >> 4;
        int f0 = fb * 32, d0 = db * 32;
        for (int i = ty; i < 32; i += 8) {
            int f = f0 + i;
            if (f < F_) tile[i][tx] = resT[((size_t)(b * F_ + f)) * D_ + d0 + tx];
        }
        __syncthreads();
        bool fok = (f0 + tx) < F_;
        for (int i = ty; i < 32; i += 8) {
            if (fok) {
                size_t o = ((size_t)b * D_ + d0 + i) * F_ + f0 + tx;
                out[o] = lat[o] - tile[tx][i];
            }
        }
        __syncthreads();
    }
}

__global__ void k_codes(const int* __restrict__ codes, float* __restrict__ out1) {
    int bi = blockIdx.x;
    int q = bi & 7, b = bi >> 3;
    for (int f = threadIdx.x; f < F_; f += 256)
        out1[(size_t)bi * F_ + f] = (float)codes[(size_t)q * N_ + (size_t)b * F_ + f];
}

__global__ void k_loss(const double* __restrict__ part, float* __restrict__ out2) {
    double s = 0.0;
    for (int i = threadIdx.x; i < Q_ * UPDBLK; i += 256) s += part[i];
#pragma unroll
    for (int off = 32; off; off >>= 1) s += __shfl_down(s, off, 64);
    __shared__ double red[4];
    int lane = threadIdx.x & 63, wv = threadIdx.x >> 6;
    if (lane == 0) red[wv] = s;
    __syncthreads();
    if (threadIdx.x == 0) {
        double tot = red[0] + red[1] + red[2] + red[3];
        float val = (float)(tot / ((double)Q_ * (double)B_ * (double)D_ * (double)F_));
        out2[0] = val;
        out2[1] = val;
    }
}

extern "C" void kernel_launch(void* const* d_in, const int* in_sizes, int n_in,
                              void* d_out, int out_size, void* d_ws, size_t ws_size,
                              hipStream_t stream) {
    const float* lat = (const float*)d_in[0];   // [16,512,1500] fp32
    const float* cb  = (const float*)d_in[1];   // [8,1024,512]  fp32
    char* ws = (char*)d_ws;
    float*    resT  = (float*)(ws);                          // 49,283,072
    short*    resbf = (short*)(ws + 49283072);               // 24,641,536
    short*    cbh   = (short*)(ws + 73924608);               //  8,388,608
    unsigned* candB = (unsigned*)(ws + 82313216);            //  6,144,000
    float*    Dmin  = (float*)(ws + 88457216);               //    768,000
    unsigned* cnt8  = (unsigned*)(ws + 89225216);            //    768,000
    int*      codes = (int*)(ws + 89993216);                 //    768,000
    float*    Hq    = (float*)(ws + 90761216);               //     32,768
    float*    Sp    = (float*)(ws + 90793984);               //    384,000
    double*   part  = (double*)(ws + 91177984);              //     24,064
    float* out = (float*)d_out;

    hipLaunchKernelGGL(k_initT,    dim3(512), dim3(256), 0, stream, lat, resT, resbf);
    hipLaunchKernelGGL(k_cbh,      dim3(512), dim3(256), 0, stream, cb, cbh);
    hipLaunchKernelGGL(k_cbnormP,  dim3(Q_ * C_ / 256), dim3(256), 0, stream, cb, Hq);
    hipLaunchKernelGGL(k_rownorm4, dim3(NBLK), dim3(256), 0, stream, resT, Sp);

    for (int q = 0; q < Q_; ++q) {
        hipLaunchKernelGGL(k_gemm,     dim3(MPAD / 256, C_ / 128), dim3(256), 0, stream,
                           resbf, cbh, Hq, Dmin, candB, cnt8, q);
        hipLaunchKernelGGL(k_collect2, dim3(512), dim3(256), 0, stream,
                           Dmin, candB, cnt8, resT, cb, Hq, Sp, codes, q);
        hipLaunchKernelGGL(k_upd,      dim3(UPDBLK), dim3(256), 0, stream,
                           resT, resbf, cb, codes, Sp, part, q);
    }

    hipLaunchKernelGGL(k_out0T, dim3(512), dim3(256), 0, stream, lat, resT, out);
    hipLaunchKernelGGL(k_codes, dim3(B_ * Q_), dim3(256), 0, stream, codes, out + 12288000);
    hipLaunchKernelGGL(k_loss,  dim3(1), dim3(256), 0, stream, part, out + 12480000);
}

// Round 13
// 1652.053 us; speedup vs baseline: 14.0997x; 1.2761x over previous
//
#include <hip/hip_runtime.h>
#include <hip/hip_fp16.h>

// ResidualVectorQuantizer: B=16, D=512, F=1500, Q=8, C=1024
#define B_ 16
#define D_ 512
#define F_ 1500
#define N_ (B_*F_)   // 24000
#define Q_ 8
#define C_ 1024

constexpr int NBLK  = (N_ + 255) / 256;   // 94
constexpr int UPDBLK = 4 * NBLK;          // 376
constexpr int MPAD = 24064;               // padded rows (188*128)
constexpr int FB_  = (F_ + 31) / 32;      // 47
constexpr int TILES_ = B_ * 16 * FB_;     // 12032 transpose tiles

typedef __attribute__((ext_vector_type(8))) short bf16x8;
typedef __attribute__((ext_vector_type(4))) float f32x4;

__device__ __forceinline__ short f2bf(float f) {
    unsigned u = __float_as_uint(f);
    u += 0x7FFFu + ((u >> 16) & 1u);
    return (short)(u >> 16);
}
__device__ __forceinline__ float h2f(unsigned short u) {
    __half_raw r; r.x = u; return __half2float(__half(r));
}
__device__ __forceinline__ unsigned short f2h(float f) {
    __half h = __float2half(f);
    return __half_as_ushort(h);
}

// ---------------- init: resT/resbf[b*F+f][d] = lat[b][d][f] (grid-stride tiles) ----------------
__global__ __launch_bounds__(256) void k_initT(const float* __restrict__ lat,
                                               float* __restrict__ resT,
                                               short* __restrict__ resbf) {
    __shared__ float tile[32][33];
    int tx = threadIdx.x & 31, ty = threadIdx.x >> 5;
    for (int bi = blockIdx.x; bi < TILES_; bi += 512) {
        int fb = bi % FB_, rem = bi / FB_;
        int db = rem & 15, b = rem >> 4;
        int f0 = fb * 32, d0 = db * 32;
        bool fok = (f0 + tx) < F_;
        for (int i = ty; i < 32; i += 8)
            if (fok) tile[i][tx] = lat[((size_t)b * D_ + d0 + i) * F_ + f0 + tx];
        __syncthreads();
        for (int i = ty; i < 32; i += 8) {
            int f = f0 + i;
            if (f < F_) {
                float v = tile[tx][i];
                size_t o = ((size_t)(b * F_ + f)) * D_ + d0 + tx;
                resT[o] = v;
                resbf[o] = f2bf(v);
            }
        }
        __syncthreads();
    }
}

// ---------------- cbh = bf16(cb) (grid-stride) ----------------
__global__ void k_cbh(const float* __restrict__ cb, short* __restrict__ cbh) {
    for (int g = blockIdx.x * 256 + threadIdx.x; g < Q_ * C_ * D_ / 8; g += 512 * 256) {
        size_t base = (size_t)g * 8;
        float4 a = *(const float4*)(cb + base);
        float4 b = *(const float4*)(cb + base + 4);
        bf16x8 o;
        o[0]=f2bf(a.x); o[1]=f2bf(a.y); o[2]=f2bf(a.z); o[3]=f2bf(a.w);
        o[4]=f2bf(b.x); o[5]=f2bf(b.y); o[6]=f2bf(b.z); o[7]=f2bf(b.w);
        *(bf16x8*)(cbh + base) = o;
    }
}

// ---------------- H[q*C+c] = np.sum(cb*cb, axis=1), numpy pairwise fp32 (verified) ----------------
__global__ void k_cbnormP(const float* __restrict__ cb, float* __restrict__ Hq) {
#pragma clang fp contract(off)
    int wid = blockIdx.x * 256 + threadIdx.x;
    const float* p = cb + (size_t)wid * D_;
    float L[4];
#pragma unroll
    for (int l = 0; l < 4; ++l) {
        const float* pl = p + l * 128;
        float r[8];
#pragma unroll
        for (int j = 0; j < 8; ++j) { float x = pl[j]; r[j] = x * x; }
        for (int i = 8; i < 128; i += 8) {
#pragma unroll
            for (int j = 0; j < 8; ++j) { float x = pl[i + j]; r[j] = r[j] + x * x; }
        }
        L[l] = ((r[0] + r[1]) + (r[2] + r[3])) + ((r[4] + r[5]) + (r[6] + r[7]));
    }
    Hq[wid] = (L[0] + L[1]) + (L[2] + L[3]);
}

// ---------------- initial S partials (verified chain) ----------------
__global__ void k_rownorm4(const float* __restrict__ resT, float* __restrict__ Sp) {
#pragma clang fp contract(off)
    int n = blockIdx.x * 256 + threadIdx.x;
    if (n >= N_) return;
#pragma unroll
    for (int l = 0; l < 4; ++l) {
        const float* p = resT + (size_t)n * D_ + l * 128;
        float r[8];
#pragma unroll
        for (int j = 0; j < 8; ++j) { float x = p[j]; r[j] = x * x; }
        for (int i = 8; i < 128; i += 8) {
#pragma unroll
            for (int j = 0; j < 8; ++j) { float x = p[i + j]; r[j] = r[j] + x * x; }
        }
        Sp[(size_t)l * N_ + n] = ((r[0] + r[1]) + (r[2] + r[3])) + ((r[4] + r[5]) + (r[6] + r[7]));
    }
}

// ---------------- bf16 MFMA screen GEMM: per-row-block candidate slots (2 n-tiles/block) ----------------
#define LSTR 80
__global__ __launch_bounds__(256) void k_gemm(
        const short* __restrict__ resbf, const short* __restrict__ cbh,
        const float* __restrict__ Hq, float* __restrict__ Dmin,
        unsigned* __restrict__ candBuf, unsigned* __restrict__ cnt8,
        int* __restrict__ gwork, int q) {
    __shared__ short xh[128 * LSTR];
    __shared__ short ch[128 * LSTR];
    __shared__ float smin[128][2];
    __shared__ float bminL[128];
    __shared__ unsigned lcnt[128];
    __shared__ unsigned slots[128][8];

    const int t = threadIdx.x;
    if (blockIdx.x == 0 && blockIdx.y == 0 && t == 0) *gwork = 0;
    const int cby = blockIdx.y;
    const int c0 = cby * 128;
    const int l = t & 63, w = t >> 6;
    const int wr = w >> 1, wc = w & 1;
    const short* cbhq = cbh + ((size_t)q * C_) * D_;
    const float* Hqq = Hq + (size_t)q * C_;

    for (int nt = 0; nt < 2; ++nt) {
        const int n0 = (blockIdx.x * 2 + nt) * 128;

        f32x4 acc[4][4];
#pragma unroll
        for (int i = 0; i < 4; ++i)
#pragma unroll
            for (int j = 0; j < 4; ++j) { acc[i][j][0]=0.f; acc[i][j][1]=0.f; acc[i][j][2]=0.f; acc[i][j][3]=0.f; }

        for (int kc = 0; kc < D_; kc += 64) {
            __syncthreads();
#pragma unroll
            for (int p = 0; p < 4; ++p) {
                int idx = p * 256 + t;
                int nn = idx >> 3, d8 = idx & 7;
                *(bf16x8*)(&xh[nn * LSTR + d8 * 8]) =
                    *(const bf16x8*)(resbf + (size_t)(n0 + nn) * D_ + kc + d8 * 8);
            }
#pragma unroll
            for (int p = 0; p < 4; ++p) {
                int idx = p * 256 + t;
                int cr = idx >> 3, d8 = idx & 7;
                *(bf16x8*)(&ch[cr * LSTR + d8 * 8]) =
                    *(const bf16x8*)(cbhq + (size_t)(c0 + cr) * D_ + kc + d8 * 8);
            }
            __syncthreads();

#pragma unroll
            for (int kf = 0; kf < 2; ++kf) {
                const int ko = kf * 32 + (l >> 4) * 8;
                bf16x8 ah[4], bh[4];
#pragma unroll
                for (int i = 0; i < 4; ++i) {
                    ah[i] = *(const bf16x8*)(&xh[(wr * 64 + i * 16 + (l & 15)) * LSTR + ko]);
                    bh[i] = *(const bf16x8*)(&ch[(wc * 64 + i * 16 + (l & 15)) * LSTR + ko]);
                }
#pragma unroll
                for (int i = 0; i < 4; ++i)
#pragma unroll
                    for (int j = 0; j < 4; ++j)
                        acc[i][j] = __builtin_amdgcn_mfma_f32_16x16x32_bf16(ah[i], bh[j], acc[i][j], 0, 0, 0);
            }
        }

        float hv[4];
#pragma unroll
        for (int j = 0; j < 4; ++j) hv[j] = Hqq[c0 + wc * 64 + j * 16 + (l & 15)];

        // pass 1: row minima of (H - 2A)
#pragma unroll
        for (int i = 0; i < 4; ++i)
#pragma unroll
            for (int r = 0; r < 4; ++r) {
                float vm = hv[0] - 2.0f * acc[i][0][r];
#pragma unroll
                for (int j = 1; j < 4; ++j) vm = fminf(vm, hv[j] - 2.0f * acc[i][j][r]);
                vm = fminf(vm, __shfl_xor(vm, 1, 64));
                vm = fminf(vm, __shfl_xor(vm, 2, 64));
                vm = fminf(vm, __shfl_xor(vm, 4, 64));
                vm = fminf(vm, __shfl_xor(vm, 8, 64));
                if ((l & 15) == 0) smin[wr * 64 + i * 16 + (l >> 4) * 4 + r][wc] = vm;
            }
        __syncthreads();
        if (t < 128) {
            bminL[t] = fminf(smin[t][0], smin[t][1]);
            lcnt[t] = 0;
        }
        __syncthreads();
        // pass 2: emit slots within blockmin + 1.6e-3
#pragma unroll
        for (int i = 0; i < 4; ++i)
#pragma unroll
            for (int j = 0; j < 4; ++j)
#pragma unroll
                for (int r = 0; r < 4; ++r) {
                    int row = wr * 64 + i * 16 + (l >> 4) * 4 + r;
                    float v = hv[j] - 2.0f * acc[i][j][r];
                    if (v <= bminL[row] + 1.6e-3f) {
                        unsigned pos = atomicAdd(&lcnt[row], 1u);
                        if (pos < 8) {
                            unsigned c = (unsigned)(c0 + wc * 64 + j * 16 + (l & 15));
                            slots[row][pos] = ((unsigned)f2h(v) << 16) | c;
                        }
                    }
                }
        __syncthreads();
        if (t < 128 && (n0 + t) < N_) {
            int n = n0 + t;
            Dmin[(size_t)n * 8 + cby] = bminL[t];
            unsigned cnt = lcnt[t];
            cnt8[(size_t)n * 8 + cby] = cnt;
            unsigned mm = cnt < 8u ? cnt : 8u;
            for (unsigned s = 0; s < mm; ++s)
                candBuf[((size_t)n * 8 + cby) * 8 + s] = slots[t][s];
        }
        __syncthreads();
    }
}

// ---------------- collect: fast path + compact worklist (block-aggregated, 1 atomic/block) ----------------
__global__ __launch_bounds__(256) void k_collect3(
        const float* __restrict__ Dmin, const unsigned* __restrict__ candBuf,
        const unsigned* __restrict__ cnt8, const float* __restrict__ resT,
        const float* __restrict__ cb, const float* __restrict__ Hq,
        const float* __restrict__ Sp, int* __restrict__ codes,
        unsigned long long* __restrict__ rkey, unsigned* __restrict__ work,
        int* __restrict__ gwork, int q) {
#pragma clang fp contract(off)
    __shared__ unsigned witems[400];
    __shared__ unsigned wcnt;
    __shared__ int sbase;
    const int w = threadIdx.x >> 6, lane = threadIdx.x & 63;
    if (threadIdx.x == 0) wcnt = 0;
    __syncthreads();
    const float* cbq = cb + (size_t)q * ((size_t)C_ * D_);
    const float* Hqq = Hq + (size_t)q * C_;

    for (int n = blockIdx.x * 4 + w; n < N_; n += 2048) {
        float dml = 3.4e38f; unsigned cl = 0u;
        if (lane < 8) { dml = Dmin[(size_t)n * 8 + lane]; cl = cnt8[(size_t)n * 8 + lane]; }
        float m = dml;
        m = fminf(m, __shfl_xor(m, 4, 64));
        m = fminf(m, __shfl_xor(m, 2, 64));
        m = fminf(m, __shfl_xor(m, 1, 64));
        m = __shfl(m, 0, 64);
        const float thr = m + 1.5e-3f;

        bool ovf = __any(lane < 8 && cl > 8u && dml <= thr + 1e-4f);
        if (!ovf) {
            int blk = lane >> 3, s = lane & 7;
            unsigned cb8 = __shfl(cl, blk, 64);
            if (cb8 > 8u) cb8 = 8u;
            bool has = false; int myc = 0x7fffffff;
            if ((unsigned)s < cb8) {
                unsigned e = candBuf[((size_t)n * 8 + blk) * 8 + s];
                if (h2f((unsigned short)(e >> 16)) <= thr) { has = true; myc = (int)(e & 0x3FFu); }
            }
            unsigned long long mask = __ballot(has);
            int tot = __popcll(mask);
            if (tot == 1) {
                int src = __ffsll((unsigned long long)mask) - 1;
                int code = __shfl(myc, src, 64);
                if (lane == 0) codes[(size_t)q * N_ + n] = code;
                continue;
            }
            if (tot <= 8) {   // 2..8 candidates -> worklist
                if (lane == 0) { rkey[n] = ~0ull; codes[(size_t)q * N_ + n] = -1; }
                if (has) {
                    unsigned pos = atomicAdd(&wcnt, 1u);
                    witems[pos] = ((unsigned)n << 10) | (unsigned)myc;
                }
                continue;
            }
            ovf = true;
        }
        {   // rare fallback: approx full row + exact-chain shortlist
            float S = (Sp[n] + Sp[N_ + n]) + (Sp[2 * N_ + n] + Sp[3 * N_ + n]);
            const float4* xr4 = (const float4*)(resT + (size_t)n * D_);
            float mn = 3.4e38f;
            for (int rep = 0; rep < 16; ++rep) {
                int c = lane + rep * 64;
                const float4* cr4 = (const float4*)(cbq + (size_t)c * D_);
                float a0 = 0.f, a1 = 0.f, a2 = 0.f, a3 = 0.f;
#pragma unroll 4
                for (int d4 = 0; d4 < 128; ++d4) {
                    float4 xv = xr4[d4], cv = cr4[d4];
                    a0 = fmaf(xv.x, cv.x, a0); a1 = fmaf(xv.y, cv.y, a1);
                    a2 = fmaf(xv.z, cv.z, a2); a3 = fmaf(xv.w, cv.w, a3);
                }
                float v = (S - 2.0f * ((a0 + a1) + (a2 + a3))) + Hqq[c];
                mn = fminf(mn, v);
            }
            for (int off = 32; off; off >>= 1) mn = fminf(mn, __shfl_xor(mn, off, 64));
            const float thr2 = mn + 6e-4f;
            float bv = 3.4e38f; int bc = 0x7fffffff;
            const float* xr = resT + (size_t)n * D_;
            for (int rep = 0; rep < 16; ++rep) {
                int c = lane + rep * 64;
                const float4* cr4 = (const float4*)(cbq + (size_t)c * D_);
                float a0 = 0.f, a1 = 0.f, a2 = 0.f, a3 = 0.f;
#pragma unroll 4
                for (int d4 = 0; d4 < 128; ++d4) {
                    float4 xv = xr4[d4], cv = cr4[d4];
                    a0 = fmaf(xv.x, cv.x, a0); a1 = fmaf(xv.y, cv.y, a1);
                    a2 = fmaf(xv.z, cv.z, a2); a3 = fmaf(xv.w, cv.w, a3);
                }
                float vap = (S - 2.0f * ((a0 + a1) + (a2 + a3))) + Hqq[c];
                if (vap <= thr2) {
                    const float* cr = cbq + (size_t)c * D_;
                    float A = 0.0f;
#pragma unroll 8
                    for (int d = 0; d < D_; ++d) A = fmaf(xr[d], cr[d], A);
                    float v = (S - 2.0f * A) + Hqq[c];
                    if (v < bv || (v == bv && c < bc)) { bv = v; bc = c; }
                }
            }
            for (int off = 32; off; off >>= 1) {
                float ov = __shfl_xor(bv, off, 64);
                int oc = __shfl_xor(bc, off, 64);
                if (ov < bv || (ov == bv && oc < bc)) { bv = ov; bc = oc; }
            }
            if (lane == 0) codes[(size_t)q * N_ + n] = bc;
        }
    }
    __syncthreads();
    if (threadIdx.x == 0) sbase = atomicAdd(gwork, (int)wcnt);
    __syncthreads();
    for (unsigned i = threadIdx.x; i < wcnt; i += 256) work[sbase + i] = witems[i];
}

// ---------------- rescore: dense thread-per-candidate, exact chain, per-row atomicMin ----------------
__global__ __launch_bounds__(256) void k_rescore2(
        const unsigned* __restrict__ work, const int* __restrict__ gwork,
        const float* __restrict__ resT, const float* __restrict__ cb,
        const float* __restrict__ Hq, const float* __restrict__ Sp,
        unsigned long long* __restrict__ rkey, int q) {
#pragma clang fp contract(off)
    int tot = *gwork;
    for (int i = blockIdx.x * 256 + threadIdx.x; i < tot; i += 96 * 256) {
        unsigned e = work[i];
        int n = (int)(e >> 10), c = (int)(e & 0x3FFu);
        float S = (Sp[n] + Sp[N_ + n]) + (Sp[2 * N_ + n] + Sp[3 * N_ + n]);
        const float* xr = resT + (size_t)n * D_;
        const float* cr = cb + ((size_t)q * C_ + c) * D_;
        float A = 0.0f;
#pragma unroll 8
        for (int d = 0; d < D_; ++d) A = fmaf(xr[d], cr[d], A);   // verified exact chain
        float v = (S - 2.0f * A) + Hq[(size_t)q * C_ + c];
        unsigned long long key = ((unsigned long long)__float_as_uint(v) << 32) | (unsigned)c;
        atomicMin(&rkey[n], key);
    }
}

// ---------------- fused residual update + bf16 shadow + S partials + loss (verified) ----------------
__global__ __launch_bounds__(256) void k_upd(
        float* __restrict__ resT, short* __restrict__ resbf,
        const float* __restrict__ cb, int* __restrict__ codes,
        const unsigned long long* __restrict__ rkey,
        float* __restrict__ Sp, double* __restrict__ part, int q) {
#pragma clang fp contract(off)
    int seg = blockIdx.x / NBLK;
    int nb  = blockIdx.x % NBLK;
    int n = nb * 256 + threadIdx.x;
    float L = 0.0f;
    if (n < N_) {
        int idx = codes[(size_t)q * N_ + n];
        if (idx < 0) idx = (int)(rkey[n] & 0x3FFull);
        if (seg == 0) codes[(size_t)q * N_ + n] = idx;   // benign same-value race
        const float* crow = cb + ((size_t)q * C_ + idx) * D_ + seg * 128;
        float* rp = resT + (size_t)n * D_ + seg * 128;
        short* rb = resbf + (size_t)n * D_ + seg * 128;
        float r8[8];
#pragma unroll
        for (int j = 0; j < 8; ++j) {
            float r = rp[j] - crow[j];
            rp[j] = r; rb[j] = f2bf(r);
            r8[j] = r * r;
        }
        for (int i = 8; i < 128; i += 8) {
#pragma unroll
            for (int j = 0; j < 8; ++j) {
                float r = rp[i + j] - crow[i + j];
                rp[i + j] = r; rb[i + j] = f2bf(r);
                r8[j] = r8[j] + r * r;
            }
        }
        L = ((r8[0] + r8[1]) + (r8[2] + r8[3])) + ((r8[4] + r8[5]) + (r8[6] + r8[7]));
        Sp[(size_t)seg * N_ + n] = L;
    }
    double s = (double)L;
#pragma unroll
    for (int off = 32; off; off >>= 1) s += __shfl_down(s, off, 64);
    __shared__ double sred[4];
    int lane = threadIdx.x & 63, wv = threadIdx.x >> 6;
    if (lane == 0) sred[wv] = s;
    __syncthreads();
    if (threadIdx.x == 0)
        part[(size_t)q * UPDBLK + blockIdx.x] = sred[0] + sred[1] + sred[2] + sred[3];
}

// ---------------- outputs ----------------
__global__ __launch_bounds__(256) void k_out0T(const float* __restrict__ lat,
                                               const float* __restrict__ resT,
                                               float* __restrict__ out) {
    __shared__ float tile[32][33];
    int tx = threadIdx.x & 31, ty = threadIdx.x >> 5;
    for (int bi = blockIdx.x; bi < TILES_; bi += 512) {
        int fb = bi % FB_, rem = bi / FB_;
        int db = rem & 15, b = rem >> 4;
        int f0 = fb * 32, d0 = db * 32;
        for (int i = ty; i < 32; i += 8) {
            int f = f0 + i;
            if (f < F_) tile[i][tx] = resT[((size_t)(b * F_ + f)) * D_ + d0 + tx];
        }
        __syncthreads();
        bool fok = (f0 + tx) < F_;
        for (int i = ty; i < 32; i += 8) {
            if (fok) {
                size_t o = ((size_t)b * D_ + d0 + i) * F_ + f0 + tx;
                out[o] = lat[o] - tile[tx][i];
            }
        }
        __syncthreads();
    }
}

__global__ void k_codes(const int* __restrict__ codes, float* __restrict__ out1) {
    int bi = blockIdx.x;
    int q = bi & 7, b = bi >> 3;
    for (int f = threadIdx.x; f < F_; f += 256)
        out1[(size_t)bi * F_ + f] = (float)codes[(size_t)q * N_ + (size_t)b * F_ + f];
}

__global__ void k_loss(const double* __restrict__ part, float* __restrict__ out2) {
    double s = 0.0;
    for (int i = threadIdx.x; i < Q_ * UPDBLK; i += 256) s += part[i];
#pragma unroll
    for (int off = 32; off; off >>= 1) s += __shfl_down(s, off, 64);
    __shared__ double red[4];
    int lane = threadIdx.x & 63, wv = threadIdx.x >> 6;
    if (lane == 0) red[wv] = s;
    __syncthreads();
    if (threadIdx.x == 0) {
        double tot = red[0] + red[1] + red[2] + red[3];
        float val = (float)(tot / ((double)Q_ * (double)B_ * (double)D_ * (double)F_));
        out2[0] = val;
        out2[1] = val;
    }
}

extern "C" void kernel_launch(void* const* d_in, const int* in_sizes, int n_in,
                              void* d_out, int out_size, void* d_ws, size_t ws_size,
                              hipStream_t stream) {
    const float* lat = (const float*)d_in[0];   // [16,512,1500] fp32
    const float* cb  = (const float*)d_in[1];   // [8,1024,512]  fp32
    char* ws = (char*)d_ws;
    float*    resT  = (float*)(ws);                          // 49,283,072
    short*    resbf = (short*)(ws + 49283072);               // 24,641,536
    short*    cbh   = (short*)(ws + 73924608);               //  8,388,608
    unsigned* candB = (unsigned*)(ws + 82313216);            //  6,144,000
    float*    Dmin  = (float*)(ws + 88457216);               //    768,000
    unsigned* cnt8  = (unsigned*)(ws + 89225216);            //    768,000
    int*      codes = (int*)(ws + 89993216);                 //    768,000
    float*    Hq    = (float*)(ws + 90761216);               //     32,768
    float*    Sp    = (float*)(ws + 90793984);               //    384,000
    double*   part  = (double*)(ws + 91177984);              //     24,064
    unsigned long long* rkey = (unsigned long long*)(ws + 91202048); // 192,000
    unsigned* work  = (unsigned*)(ws + 91394048);            //    768,000
    int*      gwork = (int*)(ws + 92162048);                 //         64
    float* out = (float*)d_out;

    hipLaunchKernelGGL(k_initT,    dim3(512), dim3(256), 0, stream, lat, resT, resbf);
    hipLaunchKernelGGL(k_cbh,      dim3(512), dim3(256), 0, stream, cb, cbh);
    hipLaunchKernelGGL(k_cbnormP,  dim3(Q_ * C_ / 256), dim3(256), 0, stream, cb, Hq);
    hipLaunchKernelGGL(k_rownorm4, dim3(NBLK), dim3(256), 0, stream, resT, Sp);

    for (int q = 0; q < Q_; ++q) {
        hipLaunchKernelGGL(k_gemm,     dim3(MPAD / 256, C_ / 128), dim3(256), 0, stream,
                           resbf, cbh, Hq, Dmin, candB, cnt8, gwork, q);
        hipLaunchKernelGGL(k_collect3, dim3(512), dim3(256), 0, stream,
                           Dmin, candB, cnt8, resT, cb, Hq, Sp, codes, rkey, work, gwork, q);
        hipLaunchKernelGGL(k_rescore2, dim3(96), dim3(256), 0, stream,
                           work, gwork, resT, cb, Hq, Sp, rkey, q);
        hipLaunchKernelGGL(k_upd,      dim3(UPDBLK), dim3(256), 0, stream,
                           resT, resbf, cb, codes, rkey, Sp, part, q);
    }

    hipLaunchKernelGGL(k_out0T, dim3(512), dim3(256), 0, stream, lat, resT, out);
    hipLaunchKernelGGL(k_codes, dim3(B_ * Q_), dim3(256), 0, stream, codes, out + 12288000);
    hipLaunchKernelGGL(k_loss,  dim3(1), dim3(256), 0, stream, part, out + 12480000);
}

// Round 14
// 1282.592 us; speedup vs baseline: 18.1612x; 1.2881x over previous
//
#include <hip/hip_runtime.h>
#include <hip/hip_fp16.h>

// ResidualVectorQuantizer: B=16, D=512, F=1500, Q=8, C=1024
#define B_ 16
#define D_ 512
#define F_ 1500
#define N_ (B_*F_)   // 24000
#define Q_ 8
#define C_ 1024

constexpr int NBLK  = (N_ + 255) / 256;   // 94
constexpr int UPDBLK = 4 * NBLK;          // 376
constexpr int MPAD = 24064;
constexpr int FB_  = (F_ + 31) / 32;      // 47
constexpr int TILES_ = B_ * 16 * FB_;     // 12032

typedef __attribute__((ext_vector_type(8))) short bf16x8;
typedef __attribute__((ext_vector_type(4))) short bf16x4;
typedef __attribute__((ext_vector_type(4))) float f32x4;

__device__ __forceinline__ short f2bf(float f) {
    unsigned u = __float_as_uint(f);
    u += 0x7FFFu + ((u >> 16) & 1u);
    return (short)(u >> 16);
}
__device__ __forceinline__ float h2f(unsigned short u) {
    __half_raw r; r.x = u; return __half2float(__half(r));
}
__device__ __forceinline__ unsigned short f2h(float f) {
    __half h = __float2half(f);
    return __half_as_ushort(h);
}

// ---------------- init: resT/resbf[b*F+f][d] = lat[b][d][f], float4 both sides ----------------
__global__ __launch_bounds__(256) void k_initT(const float* __restrict__ lat,
                                               float* __restrict__ resT,
                                               short* __restrict__ resbf) {
    __shared__ float tile[32][33];   // [d][f]
    const int t = threadIdx.x;
    const int row = t >> 3, q4 = t & 7;
    for (int bi = blockIdx.x; bi < TILES_; bi += 1024) {
        int fb = bi % FB_, rem = bi / FB_;
        int db = rem & 15, b = rem >> 4;
        int f0 = fb * 32, d0 = db * 32;
        {   // load: lat[b][d0+row][f0+4q4..+3] -> tile[row][4q4+k]
            int fbase = f0 + 4 * q4;
            const float* lp = lat + ((size_t)b * D_ + d0 + row) * F_ + fbase;
            if (fbase + 3 < F_) {
                float4 v = *(const float4*)lp;
                tile[row][4*q4+0] = v.x; tile[row][4*q4+1] = v.y;
                tile[row][4*q4+2] = v.z; tile[row][4*q4+3] = v.w;
            } else {
#pragma unroll
                for (int k = 0; k < 4; ++k)
                    tile[row][4*q4+k] = (fbase + k < F_) ? lp[k] : 0.0f;
            }
        }
        __syncthreads();
        {   // write: resT[(b*F+f0+row)][d0+4q4..+3] = tile[4q4+k][row]
            int f = f0 + row;
            if (f < F_) {
                float4 v;
                v.x = tile[4*q4+0][row]; v.y = tile[4*q4+1][row];
                v.z = tile[4*q4+2][row]; v.w = tile[4*q4+3][row];
                size_t o = ((size_t)(b * F_ + f)) * D_ + d0 + 4 * q4;
                *(float4*)(resT + o) = v;
                bf16x4 s;
                s[0] = f2bf(v.x); s[1] = f2bf(v.y); s[2] = f2bf(v.z); s[3] = f2bf(v.w);
                *(bf16x4*)(resbf + o) = s;
            }
        }
        __syncthreads();
    }
}

// ---------------- cbh = bf16(cb) ----------------
__global__ void k_cbh(const float* __restrict__ cb, short* __restrict__ cbh) {
    for (int g = blockIdx.x * 256 + threadIdx.x; g < Q_ * C_ * D_ / 8; g += 512 * 256) {
        size_t base = (size_t)g * 8;
        float4 a = *(const float4*)(cb + base);
        float4 b = *(const float4*)(cb + base + 4);
        bf16x8 o;
        o[0]=f2bf(a.x); o[1]=f2bf(a.y); o[2]=f2bf(a.z); o[3]=f2bf(a.w);
        o[4]=f2bf(b.x); o[5]=f2bf(b.y); o[6]=f2bf(b.z); o[7]=f2bf(b.w);
        *(bf16x8*)(cbh + base) = o;
    }
}

// ---------------- H[q*C+c] = np.sum(cb*cb, axis=1), numpy pairwise fp32 (verified) ----------------
__global__ void k_cbnormP(const float* __restrict__ cb, float* __restrict__ Hq) {
#pragma clang fp contract(off)
    int wid = blockIdx.x * 256 + threadIdx.x;
    const float* p = cb + (size_t)wid * D_;
    float L[4];
#pragma unroll
    for (int l = 0; l < 4; ++l) {
        const float* pl = p + l * 128;
        float r[8];
#pragma unroll
        for (int j = 0; j < 8; ++j) { float x = pl[j]; r[j] = x * x; }
        for (int i = 8; i < 128; i += 8) {
#pragma unroll
            for (int j = 0; j < 8; ++j) { float x = pl[i + j]; r[j] = r[j] + x * x; }
        }
        L[l] = ((r[0] + r[1]) + (r[2] + r[3])) + ((r[4] + r[5]) + (r[6] + r[7]));
    }
    Hq[wid] = (L[0] + L[1]) + (L[2] + L[3]);
}

// ---------------- initial S partials (verified chain) ----------------
__global__ void k_rownorm4(const float* __restrict__ resT, float* __restrict__ Sp) {
#pragma clang fp contract(off)
    int n = blockIdx.x * 256 + threadIdx.x;
    if (n >= N_) return;
#pragma unroll
    for (int l = 0; l < 4; ++l) {
        const float* p = resT + (size_t)n * D_ + l * 128;
        float r[8];
#pragma unroll
        for (int j = 0; j < 8; ++j) { float x = p[j]; r[j] = x * x; }
        for (int i = 8; i < 128; i += 8) {
#pragma unroll
            for (int j = 0; j < 8; ++j) { float x = p[i + j]; r[j] = r[j] + x * x; }
        }
        Sp[(size_t)l * N_ + n] = ((r[0] + r[1]) + (r[2] + r[3])) + ((r[4] + r[5]) + (r[6] + r[7]));
    }
}

// ---------------- fused MFMA screen + collect + exact rescore: block = 64 rows x all 1024 cols ----------------
#define LSTR 80
__global__ __launch_bounds__(256) void k_gemm2(
        const short* __restrict__ resbf, const short* __restrict__ cbh,
        const float* __restrict__ resT, const float* __restrict__ cb,
        const float* __restrict__ Hq, const float* __restrict__ Sp,
        int* __restrict__ codes, int q) {
#pragma clang fp contract(off)
    __shared__ short xh[64 * LSTR];
    __shared__ short ch[128 * LSTR];
    __shared__ float smin[64][2];
    __shared__ float bminG[64];
    __shared__ unsigned lcnt[64];
    __shared__ unsigned slots[64][16];
    __shared__ unsigned witems[1024];
    __shared__ unsigned long long rkeyL[64];
    __shared__ int fbrows[64];
    __shared__ unsigned wcnt_s, fbcnt_s;

    const int t = threadIdx.x, l = t & 63, w = t >> 6;
    const int wr = w >> 1, wc = w & 1;
    const int n0 = blockIdx.x * 64;
    const short* cbhq = cbh + (size_t)q * C_ * D_;
    const float* Hqq = Hq + (size_t)q * C_;
    const float* cbq = cb + (size_t)q * ((size_t)C_ * D_);

    if (t < 64) { bminG[t] = 3.4e38f; lcnt[t] = 0; rkeyL[t] = ~0ull; }
    if (t == 0) { wcnt_s = 0; fbcnt_s = 0; }

    for (int c0 = 0; c0 < C_; c0 += 128) {
        f32x4 acc[2][4];
#pragma unroll
        for (int i = 0; i < 2; ++i)
#pragma unroll
            for (int j = 0; j < 4; ++j) { acc[i][j][0]=0.f; acc[i][j][1]=0.f; acc[i][j][2]=0.f; acc[i][j][3]=0.f; }

        for (int kc = 0; kc < D_; kc += 64) {
            __syncthreads();
            {   // stage X: 64 rows x 64 d (2 vec8/thread)
                int idx = t; int nn = idx >> 3, d8 = idx & 7;
                *(bf16x8*)(&xh[nn * LSTR + d8 * 8]) =
                    *(const bf16x8*)(resbf + (size_t)(n0 + nn) * D_ + kc + d8 * 8);
                idx = 256 + t; nn = idx >> 3; d8 = idx & 7;
                *(bf16x8*)(&xh[nn * LSTR + d8 * 8]) =
                    *(const bf16x8*)(resbf + (size_t)(n0 + nn) * D_ + kc + d8 * 8);
            }
#pragma unroll
            for (int p = 0; p < 4; ++p) {   // stage C: 128 rows x 64 d
                int idx = p * 256 + t;
                int cr = idx >> 3, d8 = idx & 7;
                *(bf16x8*)(&ch[cr * LSTR + d8 * 8]) =
                    *(const bf16x8*)(cbhq + (size_t)(c0 + cr) * D_ + kc + d8 * 8);
            }
            __syncthreads();

#pragma unroll
            for (int kf = 0; kf < 2; ++kf) {
                const int ko = kf * 32 + (l >> 4) * 8;
                bf16x8 ah[2], bh[4];
#pragma unroll
                for (int i = 0; i < 2; ++i)
                    ah[i] = *(const bf16x8*)(&xh[(wr * 32 + i * 16 + (l & 15)) * LSTR + ko]);
#pragma unroll
                for (int j = 0; j < 4; ++j)
                    bh[j] = *(const bf16x8*)(&ch[(wc * 64 + j * 16 + (l & 15)) * LSTR + ko]);
#pragma unroll
                for (int i = 0; i < 2; ++i)
#pragma unroll
                    for (int j = 0; j < 4; ++j)
                        acc[i][j] = __builtin_amdgcn_mfma_f32_16x16x32_bf16(ah[i], bh[j], acc[i][j], 0, 0, 0);
            }
        }

        float hv[4];
#pragma unroll
        for (int j = 0; j < 4; ++j) hv[j] = Hqq[c0 + wc * 64 + j * 16 + (l & 15)];

        // local row minima for this strip
#pragma unroll
        for (int i = 0; i < 2; ++i)
#pragma unroll
            for (int r = 0; r < 4; ++r) {
                float vm = hv[0] - 2.0f * acc[i][0][r];
#pragma unroll
                for (int j = 1; j < 4; ++j) vm = fminf(vm, hv[j] - 2.0f * acc[i][j][r]);
                vm = fminf(vm, __shfl_xor(vm, 1, 64));
                vm = fminf(vm, __shfl_xor(vm, 2, 64));
                vm = fminf(vm, __shfl_xor(vm, 4, 64));
                vm = fminf(vm, __shfl_xor(vm, 8, 64));
                if ((l & 15) == 0) smin[wr * 32 + i * 16 + (l >> 4) * 4 + r][wc] = vm;
            }
        __syncthreads();
        if (t < 64) bminG[t] = fminf(bminG[t], fminf(smin[t][0], smin[t][1]));
        __syncthreads();
        // emit candidates within running-min + 1.6e-3 (superset of final decision set)
#pragma unroll
        for (int i = 0; i < 2; ++i)
#pragma unroll
            for (int j = 0; j < 4; ++j)
#pragma unroll
                for (int r = 0; r < 4; ++r) {
                    int row = wr * 32 + i * 16 + (l >> 4) * 4 + r;
                    float v = hv[j] - 2.0f * acc[i][j][r];
                    if (v <= bminG[row] + 1.6e-3f) {
                        unsigned pos = atomicAdd(&lcnt[row], 1u);
                        if (pos < 16) {
                            unsigned c = (unsigned)(c0 + wc * 64 + j * 16 + (l & 15));
                            slots[row][pos] = ((unsigned)f2h(v) << 16) | c;
                        }
                    }
                }
        // next c0 begins with __syncthreads in the kc loop
    }
    __syncthreads();

    // finalize rows
    if (t < 64) {
        int n = n0 + t;
        float thr = bminG[t] + 1.5e-3f;
        unsigned lc = lcnt[t];
        if (lc > 16u) {
            unsigned fp = atomicAdd(&fbcnt_s, 1u);
            fbrows[fp] = t;
        } else {
            int cnt = 0, c1 = -1;
            for (unsigned s = 0; s < lc; ++s) {
                unsigned e = slots[t][s];
                if (h2f((unsigned short)(e >> 16)) <= thr) { ++cnt; if (cnt == 1) c1 = (int)(e & 0x3FFu); }
            }
            if (cnt == 1) {
                codes[(size_t)q * N_ + n] = c1;
            } else {
                for (unsigned s = 0; s < lc; ++s) {
                    unsigned e = slots[t][s];
                    if (h2f((unsigned short)(e >> 16)) <= thr) {
                        unsigned pos = atomicAdd(&wcnt_s, 1u);
                        witems[pos] = ((unsigned)t << 10) | (e & 0x3FFu);
                    }
                }
            }
        }
    }
    __syncthreads();

    // dense exact-chain rescore of deferred candidates (verified chain + lex tie)
    {
        unsigned wn = wcnt_s;
        for (unsigned i = t; i < wn; i += 256) {
            unsigned e = witems[i];
            int lr = (int)(e >> 10), c = (int)(e & 0x3FFu);
            int n = n0 + lr;
            float S = (Sp[n] + Sp[N_ + n]) + (Sp[2 * N_ + n] + Sp[3 * N_ + n]);
            const float* xr = resT + (size_t)n * D_;
            const float* cr = cbq + (size_t)c * D_;
            float A = 0.0f;
#pragma unroll 8
            for (int d = 0; d < D_; ++d) A = fmaf(xr[d], cr[d], A);
            float v = (S - 2.0f * A) + Hqq[c];
            unsigned long long key = ((unsigned long long)__float_as_uint(v) << 32) | (unsigned)c;
            atomicMin(&rkeyL[lr], key);
        }
    }
    __syncthreads();
    if (t < 64 && rkeyL[t] != ~0ull)
        codes[(size_t)q * N_ + n0 + t] = (int)(rkeyL[t] & 0x3FFull);

    // rare full-row fallback (wave per row)
    {
        unsigned fn = fbcnt_s;
        for (unsigned fi = w; fi < fn; fi += 4) {
            int n = n0 + fbrows[fi];
            float S = (Sp[n] + Sp[N_ + n]) + (Sp[2 * N_ + n] + Sp[3 * N_ + n]);
            const float4* xr4 = (const float4*)(resT + (size_t)n * D_);
            float mn = 3.4e38f;
            for (int rep = 0; rep < 16; ++rep) {
                int c = l + rep * 64;
                const float4* cr4 = (const float4*)(cbq + (size_t)c * D_);
                float a0 = 0.f, a1 = 0.f, a2 = 0.f, a3 = 0.f;
#pragma unroll 4
                for (int d4 = 0; d4 < 128; ++d4) {
                    float4 xv = xr4[d4], cv = cr4[d4];
                    a0 = fmaf(xv.x, cv.x, a0); a1 = fmaf(xv.y, cv.y, a1);
                    a2 = fmaf(xv.z, cv.z, a2); a3 = fmaf(xv.w, cv.w, a3);
                }
                float v = (S - 2.0f * ((a0 + a1) + (a2 + a3))) + Hqq[c];
                mn = fminf(mn, v);
            }
            for (int off = 32; off; off >>= 1) mn = fminf(mn, __shfl_xor(mn, off, 64));
            const float thr2 = mn + 6e-4f;
            float bv = 3.4e38f; int bc = 0x7fffffff;
            const float* xr = resT + (size_t)n * D_;
            for (int rep = 0; rep < 16; ++rep) {
                int c = l + rep * 64;
                const float4* cr4 = (const float4*)(cbq + (size_t)c * D_);
                float a0 = 0.f, a1 = 0.f, a2 = 0.f, a3 = 0.f;
#pragma unroll 4
                for (int d4 = 0; d4 < 128; ++d4) {
                    float4 xv = xr4[d4], cv = cr4[d4];
                    a0 = fmaf(xv.x, cv.x, a0); a1 = fmaf(xv.y, cv.y, a1);
                    a2 = fmaf(xv.z, cv.z, a2); a3 = fmaf(xv.w, cv.w, a3);
                }
                float vap = (S - 2.0f * ((a0 + a1) + (a2 + a3))) + Hqq[c];
                if (vap <= thr2) {
                    const float* cr = cbq + (size_t)c * D_;
                    float A = 0.0f;
#pragma unroll 8
                    for (int d = 0; d < D_; ++d) A = fmaf(xr[d], cr[d], A);
                    float v = (S - 2.0f * A) + Hqq[c];
                    if (v < bv || (v == bv && c < bc)) { bv = v; bc = c; }
                }
            }
            for (int off = 32; off; off >>= 1) {
                float ov = __shfl_xor(bv, off, 64);
                int oc = __shfl_xor(bc, off, 64);
                if (ov < bv || (ov == bv && oc < bc)) { bv = ov; bc = oc; }
            }
            if (l == 0) codes[(size_t)q * N_ + n] = bc;
        }
    }
}

// ---------------- fused residual update + bf16 shadow + S partials + loss (verified, float4) ----------------
__global__ __launch_bounds__(256) void k_upd(
        float* __restrict__ resT, short* __restrict__ resbf,
        const float* __restrict__ cb, const int* __restrict__ codes,
        float* __restrict__ Sp, double* __restrict__ part, int q) {
#pragma clang fp contract(off)
    int seg = blockIdx.x / NBLK;
    int nb  = blockIdx.x % NBLK;
    int n = nb * 256 + threadIdx.x;
    float L = 0.0f;
    if (n < N_) {
        int idx = codes[(size_t)q * N_ + n];
        const float4* cr4 = (const float4*)(cb + ((size_t)q * C_ + idx) * D_ + seg * 128);
        float4* rp4 = (float4*)(resT + (size_t)n * D_ + seg * 128);
        short* rb = resbf + (size_t)n * D_ + seg * 128;
        float r8[8];
#pragma unroll
        for (int k = 0; k < 16; ++k) {
            float4 a = rp4[2*k], b = rp4[2*k+1];
            float4 ca = cr4[2*k], cb2 = cr4[2*k+1];
            float v0 = a.x - ca.x, v1 = a.y - ca.y, v2 = a.z - ca.z, v3 = a.w - ca.w;
            float v4 = b.x - cb2.x, v5 = b.y - cb2.y, v6 = b.z - cb2.z, v7 = b.w - cb2.w;
            rp4[2*k]   = float4{v0, v1, v2, v3};
            rp4[2*k+1] = float4{v4, v5, v6, v7};
            bf16x8 o;
            o[0]=f2bf(v0); o[1]=f2bf(v1); o[2]=f2bf(v2); o[3]=f2bf(v3);
            o[4]=f2bf(v4); o[5]=f2bf(v5); o[6]=f2bf(v6); o[7]=f2bf(v7);
            *(bf16x8*)(rb + 8*k) = o;
            if (k == 0) {
                r8[0]=v0*v0; r8[1]=v1*v1; r8[2]=v2*v2; r8[3]=v3*v3;
                r8[4]=v4*v4; r8[5]=v5*v5; r8[6]=v6*v6; r8[7]=v7*v7;
            } else {
                r8[0]=r8[0]+v0*v0; r8[1]=r8[1]+v1*v1; r8[2]=r8[2]+v2*v2; r8[3]=r8[3]+v3*v3;
                r8[4]=r8[4]+v4*v4; r8[5]=r8[5]+v5*v5; r8[6]=r8[6]+v6*v6; r8[7]=r8[7]+v7*v7;
            }
        }
        L = ((r8[0] + r8[1]) + (r8[2] + r8[3])) + ((r8[4] + r8[5]) + (r8[6] + r8[7]));
        Sp[(size_t)seg * N_ + n] = L;
    }
    double s = (double)L;
#pragma unroll
    for (int off = 32; off; off >>= 1) s += __shfl_down(s, off, 64);
    __shared__ double sred[4];
    int lane = threadIdx.x & 63, wv = threadIdx.x >> 6;
    if (lane == 0) sred[wv] = s;
    __syncthreads();
    if (threadIdx.x == 0)
        part[(size_t)q * UPDBLK + blockIdx.x] = sred[0] + sred[1] + sred[2] + sred[3];
}

// ---------------- outputs ----------------
__global__ __launch_bounds__(256) void k_out0T(const float* __restrict__ lat,
                                               const float* __restrict__ resT,
                                               float* __restrict__ out) {
    __shared__ float tile[32][33];   // [d][f]
    const int t = threadIdx.x;
    const int row = t >> 3, q4 = t & 7;
    for (int bi = blockIdx.x; bi < TILES_; bi += 1024) {
        int fb = bi % FB_, rem = bi / FB_;
        int db = rem & 15, b = rem >> 4;
        int f0 = fb * 32, d0 = db * 32;
        {   // load: resT[(b*F+f0+row)][d0+4q4..+3] -> tile[4q4+k][row]
            int f = f0 + row;
            if (f < F_) {
                float4 v = *(const float4*)(resT + ((size_t)(b * F_ + f)) * D_ + d0 + 4 * q4);
                tile[4*q4+0][row] = v.x; tile[4*q4+1][row] = v.y;
                tile[4*q4+2][row] = v.z; tile[4*q4+3][row] = v.w;
            }
        }
        __syncthreads();
        {   // write: out[b][d0+row][f0+4q4..+3] = lat - tile[row][4q4+k]
            int fbase = f0 + 4 * q4;
            size_t o = ((size_t)b * D_ + d0 + row) * F_ + fbase;
            if (fbase + 3 < F_) {
                float4 lv = *(const float4*)(lat + o);
                float4 v;
                v.x = lv.x - tile[row][4*q4+0]; v.y = lv.y - tile[row][4*q4+1];
                v.z = lv.z - tile[row][4*q4+2]; v.w = lv.w - tile[row][4*q4+3];
                *(float4*)(out + o) = v;
            } else {
#pragma unroll
                for (int k = 0; k < 4; ++k)
                    if (fbase + k < F_) out[o + k] = lat[o + k] - tile[row][4*q4+k];
            }
        }
        __syncthreads();
    }
}

__global__ void k_codes(const int* __restrict__ codes, float* __restrict__ out1) {
    int bi = blockIdx.x;
    int q = bi & 7, b = bi >> 3;
    for (int f = threadIdx.x; f < F_; f += 256)
        out1[(size_t)bi * F_ + f] = (float)codes[(size_t)q * N_ + (size_t)b * F_ + f];
}

__global__ void k_loss(const double* __restrict__ part, float* __restrict__ out2) {
    double s = 0.0;
    for (int i = threadIdx.x; i < Q_ * UPDBLK; i += 256) s += part[i];
#pragma unroll
    for (int off = 32; off; off >>= 1) s += __shfl_down(s, off, 64);
    __shared__ double red[4];
    int lane = threadIdx.x & 63, wv = threadIdx.x >> 6;
    if (lane == 0) red[wv] = s;
    __syncthreads();
    if (threadIdx.x == 0) {
        double tot = red[0] + red[1] + red[2] + red[3];
        float val = (float)(tot / ((double)Q_ * (double)B_ * (double)D_ * (double)F_));
        out2[0] = val;
        out2[1] = val;
    }
}

extern "C" void kernel_launch(void* const* d_in, const int* in_sizes, int n_in,
                              void* d_out, int out_size, void* d_ws, size_t ws_size,
                              hipStream_t stream) {
    const float* lat = (const float*)d_in[0];   // [16,512,1500] fp32
    const float* cb  = (const float*)d_in[1];   // [8,1024,512]  fp32
    char* ws = (char*)d_ws;
    float*  resT  = (float*)(ws);                 // 49,283,072
    short*  resbf = (short*)(ws + 49283072);      // 24,641,536
    short*  cbh   = (short*)(ws + 73924608);      //  8,388,608
    int*    codes = (int*)(ws + 82313216);        //    768,000
    float*  Hq    = (float*)(ws + 83081216);      //     32,768
    float*  Sp    = (float*)(ws + 83113984);      //    384,000
    double* part  = (double*)(ws + 83497984);     //     24,064
    float* out = (float*)d_out;

    hipLaunchKernelGGL(k_initT,    dim3(1024), dim3(256), 0, stream, lat, resT, resbf);
    hipLaunchKernelGGL(k_cbh,      dim3(512), dim3(256), 0, stream, cb, cbh);
    hipLaunchKernelGGL(k_cbnormP,  dim3(Q_ * C_ / 256), dim3(256), 0, stream, cb, Hq);
    hipLaunchKernelGGL(k_rownorm4, dim3(NBLK), dim3(256), 0, stream, resT, Sp);

    for (int q = 0; q < Q_; ++q) {
        hipLaunchKernelGGL(k_gemm2, dim3(N_ / 64), dim3(256), 0, stream,
                           resbf, cbh, resT, cb, Hq, Sp, codes, q);
        hipLaunchKernelGGL(k_upd,   dim3(UPDBLK), dim3(256), 0, stream,
                           resT, resbf, cb, codes, Sp, part, q);
    }

    hipLaunchKernelGGL(k_out0T, dim3(1024), dim3(256), 0, stream, lat, resT, out);
    hipLaunchKernelGGL(k_codes, dim3(B_ * Q_), dim3(256), 0, stream, codes, out + 12288000);
    hipLaunchKernelGGL(k_loss,  dim3(1), dim3(256), 0, stream, part, out + 12480000);
}